// Round 2
// baseline (780.682 us; speedup 1.0000x reference)
//
#include <hip/hip_runtime.h>

// Conditional-DETR decoder layer, MI355X gfx950.
// R7 green @ 800.9 us (prior session). R8 infra-failed twice (no counters).
// R9 (this): two low-risk changes, attribution via per-dispatch durations:
//  1) issue-early register prefetch in all MFMA kernels (m249: +3% reg-staged
//     2ph; more expected here since dispatches are latency-exposed).
//  2) softmax+head_mean fusion: one block per (b,l) does all 6 heads,
//     accumulates head-mean in regs -> kills a full 75 MB score re-read + 2
//     dispatches.
// Dtypes: inputs fp32, outputs fp32; intermediates bf16; fp32 accum everywhere.

typedef __bf16 bf16;
typedef __attribute__((ext_vector_type(8))) __bf16 bf16x8;
typedef __attribute__((ext_vector_type(4))) float f32x4;

#define D_MODEL 768
#define NH 6
#define HD 128
#define ROWSTRIDE (8 * D_MODEL)  // 6144 (B*D)

// 8-elem staging loaders -> bf16x8
__device__ inline bf16x8 ld8f(const float* p) {
    f32x4 a = *(const f32x4*)p, b = *(const f32x4*)(p + 4);
    bf16x8 r;
#pragma unroll
    for (int i = 0; i < 4; i++) { r[i] = (bf16)a[i]; r[i + 4] = (bf16)b[i]; }
    return r;
}
__device__ inline bf16x8 ld8b(const bf16* p) { return *(const bf16x8*)p; }
__device__ inline bf16x8 ld8bf(const bf16* p, const float* q) {  // bf16 + f32
    bf16x8 x = *(const bf16x8*)p;
    f32x4 a = *(const f32x4*)q, b = *(const f32x4*)(q + 4);
    bf16x8 r;
#pragma unroll
    for (int i = 0; i < 4; i++) { r[i] = (bf16)((float)x[i] + a[i]); r[i + 4] = (bf16)((float)x[i + 4] + b[i]); }
    return r;
}
__device__ inline bf16x8 ld8ff(const float* p, const float* q) {  // f32 + f32
    f32x4 a = *(const f32x4*)p, b = *(const f32x4*)(p + 4);
    f32x4 c = *(const f32x4*)q, d = *(const f32x4*)(q + 4);
    bf16x8 r;
#pragma unroll
    for (int i = 0; i < 4; i++) { r[i] = (bf16)(a[i] + c[i]); r[i + 4] = (bf16)(b[i] + d[i]); }
    return r;
}

// ---------------------------------------------------------------------------
// Multi-job GEMM: per z-slice job: C[M,N] = A[M,K] * W[N,K]^T + bias.
// aty: 0 = A fp32, 1 = A bf16, 2 = A bf16 + A2 fp32 (summed).
// 128x128 tile, 256 thr = 4 waves (2x2), 4x4 MFMA 16x16x32 per wave.
// K-loop software-pipelined: tile k+1 global->reg issue before tile k MFMAs.
struct Job { const void* A; const void* A2; const float* W; const float* bias;
             bf16* C; int aty; int relu; };
struct Jobs5 { Job j[5]; };

__device__ inline void load_a(const Job& jb, size_t off, int k0, bf16x8& r) {
    if (jb.aty == 0)      r = ld8f((const float*)jb.A + off + k0);
    else if (jb.aty == 1) r = ld8b((const bf16*)jb.A + off + k0);
    else                  r = ld8bf((const bf16*)jb.A + off + k0,
                                    (const float*)jb.A2 + off + k0);
}

__global__ __launch_bounds__(256) void gemm_jobs(
    Jobs5 jobs, int lda, int ldw, int ldc, int K)
{
    __shared__ __align__(16) bf16 As[128][40];
    __shared__ __align__(16) bf16 Bs[128][40];
    const Job jb = jobs.j[blockIdx.z];
    const int bm = blockIdx.y * 128, bn = blockIdx.x * 128;
    const int tid = threadIdx.x;
    const int wave = tid >> 6, lane = tid & 63;
    const int wm = (wave >> 1) * 64, wn = (wave & 1) * 64;
    const int quad = lane >> 4, m16 = lane & 15;
    const int srow = tid >> 2, scol = (tid & 3) * 8;
    f32x4 acc[4][4] = {};
    const size_t aoff0 = (size_t)(bm + srow) * lda + scol;
    const size_t aoff1 = aoff0 + (size_t)64 * lda;
    const size_t woff0 = (size_t)(bn + srow) * ldw + scol;
    const size_t woff1 = woff0 + (size_t)64 * ldw;
    bf16x8 a0, a1, b0, b1;
    load_a(jb, aoff0, 0, a0);
    load_a(jb, aoff1, 0, a1);
    b0 = ld8f(jb.W + woff0);
    b1 = ld8f(jb.W + woff1);
    for (int k0 = 0; k0 < K; k0 += 32) {
        *(bf16x8*)&As[srow][scol]      = a0;
        *(bf16x8*)&As[srow + 64][scol] = a1;
        *(bf16x8*)&Bs[srow][scol]      = b0;
        *(bf16x8*)&Bs[srow + 64][scol] = b1;
        __syncthreads();
        const int kn = k0 + 32;
        if (kn < K) {
            load_a(jb, aoff0, kn, a0);
            load_a(jb, aoff1, kn, a1);
            b0 = ld8f(jb.W + woff0 + kn);
            b1 = ld8f(jb.W + woff1 + kn);
        }
        bf16x8 af[4], bfr[4];
#pragma unroll
        for (int i = 0; i < 4; i++) {
            af[i]  = *(const bf16x8*)&As[wm + i * 16 + m16][quad * 8];
            bfr[i] = *(const bf16x8*)&Bs[wn + i * 16 + m16][quad * 8];
        }
#pragma unroll
        for (int i = 0; i < 4; i++)
#pragma unroll
            for (int j = 0; j < 4; j++)
                acc[i][j] = __builtin_amdgcn_mfma_f32_16x16x32_bf16(af[i], bfr[j], acc[i][j], 0, 0, 0);
        __syncthreads();
    }
#pragma unroll
    for (int j = 0; j < 4; j++) {
        const int col = bn + wn + j * 16 + m16;
        const float bv = jb.bias[col];
#pragma unroll
        for (int i = 0; i < 4; i++)
#pragma unroll
            for (int r = 0; r < 4; r++) {
                const int row = bm + wm + i * 16 + quad * 4 + r;
                float val = acc[i][j][r] + bv;
                if (jb.relu) val = fmaxf(val, 0.f);
                jb.C[(size_t)row * ldc + col] = (bf16)val;
            }
    }
}

// ---------------------------------------------------------------------------
// Split-K GEMM: z = K-slice; fp32 partial out (no bias — folded into add_ln).
// ATY 1 = bf16 A; ATY 3 = fp32+fp32 dual A (PV partial pair). Pipelined.
template <int ATY>
__global__ __launch_bounds__(256) void gemm_sk(
    const void* __restrict__ A, const void* __restrict__ A2, int lda,
    const float* __restrict__ W, int ldw,
    float* __restrict__ Cp, size_t cstride, int ldc, int Ks)
{
    __shared__ __align__(16) bf16 As[128][40];
    __shared__ __align__(16) bf16 Bs[128][40];
    const int bm = blockIdx.y * 128, bn = blockIdx.x * 128;
    const int kbase = blockIdx.z * Ks;
    const int tid = threadIdx.x;
    const int wave = tid >> 6, lane = tid & 63;
    const int wm = (wave >> 1) * 64, wn = (wave & 1) * 64;
    const int quad = lane >> 4, m16 = lane & 15;
    const int srow = tid >> 2, scol = (tid & 3) * 8;
    f32x4 acc[4][4] = {};
    const size_t aoff0 = (size_t)(bm + srow) * lda + kbase + scol;
    const size_t aoff1 = aoff0 + (size_t)64 * lda;
    const size_t woff0 = (size_t)(bn + srow) * ldw + kbase + scol;
    const size_t woff1 = woff0 + (size_t)64 * ldw;
    bf16x8 a0, a1, b0, b1;
    if (ATY == 1) {
        a0 = ld8b((const bf16*)A + aoff0);
        a1 = ld8b((const bf16*)A + aoff1);
    } else {
        a0 = ld8ff((const float*)A + aoff0, (const float*)A2 + aoff0);
        a1 = ld8ff((const float*)A + aoff1, (const float*)A2 + aoff1);
    }
    b0 = ld8f(W + woff0);
    b1 = ld8f(W + woff1);
    for (int k0 = 0; k0 < Ks; k0 += 32) {
        *(bf16x8*)&As[srow][scol]      = a0;
        *(bf16x8*)&As[srow + 64][scol] = a1;
        *(bf16x8*)&Bs[srow][scol]      = b0;
        *(bf16x8*)&Bs[srow + 64][scol] = b1;
        __syncthreads();
        const int kn = k0 + 32;
        if (kn < Ks) {
            if (ATY == 1) {
                a0 = ld8b((const bf16*)A + aoff0 + kn);
                a1 = ld8b((const bf16*)A + aoff1 + kn);
            } else {
                a0 = ld8ff((const float*)A + aoff0 + kn, (const float*)A2 + aoff0 + kn);
                a1 = ld8ff((const float*)A + aoff1 + kn, (const float*)A2 + aoff1 + kn);
            }
            b0 = ld8f(W + woff0 + kn);
            b1 = ld8f(W + woff1 + kn);
        }
        bf16x8 af[4], bfr[4];
#pragma unroll
        for (int i = 0; i < 4; i++) {
            af[i]  = *(const bf16x8*)&As[wm + i * 16 + m16][quad * 8];
            bfr[i] = *(const bf16x8*)&Bs[wn + i * 16 + m16][quad * 8];
        }
#pragma unroll
        for (int i = 0; i < 4; i++)
#pragma unroll
            for (int j = 0; j < 4; j++)
                acc[i][j] = __builtin_amdgcn_mfma_f32_16x16x32_bf16(af[i], bfr[j], acc[i][j], 0, 0, 0);
        __syncthreads();
    }
    float* out = Cp + (size_t)blockIdx.z * cstride;
#pragma unroll
    for (int j = 0; j < 4; j++) {
        const int col = bn + wn + j * 16 + m16;
#pragma unroll
        for (int i = 0; i < 4; i++)
#pragma unroll
            for (int r = 0; r < 4; r++) {
                const int row = bm + wm + i * 16 + quad * 4 + r;
                out[(size_t)row * ldc + col] = acc[i][j][r];
            }
    }
}

// ---------------------------------------------------------------------------
// scores[bh,l,s] = scale*(qc.kc + qp.kp), K=256. Grid (S/128, Lq/128, B*H).
// Pipelined like the GEMMs.
__global__ __launch_bounds__(256) void attn_scores(
    const bf16* __restrict__ qc, const bf16* __restrict__ qp,
    const bf16* __restrict__ kc, const bf16* __restrict__ kp,
    bf16* __restrict__ scores, int Lq, int S, float scale)
{
    __shared__ __align__(16) bf16 As[128][40];
    __shared__ __align__(16) bf16 Bs[128][40];
    const int bh = blockIdx.z;
    const int b = bh / NH, h = bh % NH;
    const int bm = blockIdx.y * 128, bn = blockIdx.x * 128;
    const int tid = threadIdx.x;
    const int wave = tid >> 6, lane = tid & 63;
    const int wm = (wave >> 1) * 64, wn = (wave & 1) * 64;
    const int quad = lane >> 4, m16 = lane & 15;
    const int srow = tid >> 2, scol = (tid & 3) * 8;
    f32x4 acc[4][4] = {};
    const size_t hb = (size_t)b * D_MODEL + h * HD;
    bf16x8 a0, a1, b0, b1;
    a0 = *(const bf16x8*)(qc + (size_t)(bm + srow) * ROWSTRIDE + hb + scol);
    a1 = *(const bf16x8*)(qc + (size_t)(bm + srow + 64) * ROWSTRIDE + hb + scol);
    b0 = *(const bf16x8*)(kc + (size_t)(bn + srow) * ROWSTRIDE + hb + scol);
    b1 = *(const bf16x8*)(kc + (size_t)(bn + srow + 64) * ROWSTRIDE + hb + scol);
    for (int k0 = 0; k0 < 256; k0 += 32) {
        *(bf16x8*)&As[srow][scol]      = a0;
        *(bf16x8*)&As[srow + 64][scol] = a1;
        *(bf16x8*)&Bs[srow][scol]      = b0;
        *(bf16x8*)&Bs[srow + 64][scol] = b1;
        __syncthreads();
        const int kn = k0 + 32;
        if (kn < 256) {
            const bf16* qsrc = (kn < 128) ? qc : qp;
            const bf16* ksrc = (kn < 128) ? kc : kp;
            const int kcol = (kn & 127) + scol;
            a0 = *(const bf16x8*)(qsrc + (size_t)(bm + srow) * ROWSTRIDE + hb + kcol);
            a1 = *(const bf16x8*)(qsrc + (size_t)(bm + srow + 64) * ROWSTRIDE + hb + kcol);
            b0 = *(const bf16x8*)(ksrc + (size_t)(bn + srow) * ROWSTRIDE + hb + kcol);
            b1 = *(const bf16x8*)(ksrc + (size_t)(bn + srow + 64) * ROWSTRIDE + hb + kcol);
        }
        bf16x8 af[4], bfr[4];
#pragma unroll
        for (int i = 0; i < 4; i++) {
            af[i]  = *(const bf16x8*)&As[wm + i * 16 + m16][quad * 8];
            bfr[i] = *(const bf16x8*)&Bs[wn + i * 16 + m16][quad * 8];
        }
#pragma unroll
        for (int i = 0; i < 4; i++)
#pragma unroll
            for (int j = 0; j < 4; j++)
                acc[i][j] = __builtin_amdgcn_mfma_f32_16x16x32_bf16(af[i], bfr[j], acc[i][j], 0, 0, 0);
        __syncthreads();
    }
    bf16* sb = scores + (size_t)bh * Lq * S;
#pragma unroll
    for (int i = 0; i < 4; i++)
#pragma unroll
        for (int j = 0; j < 4; j++)
#pragma unroll
            for (int r = 0; r < 4; r++)
                sb[(size_t)(bm + wm + i * 16 + quad * 4 + r) * S + bn + wn + j * 16 + m16]
                    = (bf16)(acc[i][j][r] * scale);
}

// ---------------------------------------------------------------------------
// Fused softmax + head-mean. One block per (b,l): all NH=6 head rows.
// N = S/256 elems per thread per row. Writes normalized rows back (bf16) and
// the head-averaged row (fp32) from pre-rounding values.
template <int N>
__global__ __launch_bounds__(256) void softmax_mean(
    bf16* __restrict__ scores, float* __restrict__ att, int Lq)
{
    const int S = N << 8;
    const int l = blockIdx.x, b = blockIdx.y;
    const int tid = threadIdx.x;
    __shared__ float red[4], red2[4];
    float macc[N];
#pragma unroll
    for (int i = 0; i < N; i++) macc[i] = 0.f;
    for (int h = 0; h < NH; h++) {
        bf16* p = scores + ((size_t)(b * NH + h) * Lq + l) * S;
        float vals[N];
        float mx = -1e30f;
#pragma unroll
        for (int i = 0; i < N; i++) { vals[i] = (float)p[tid + (i << 8)]; mx = fmaxf(mx, vals[i]); }
        for (int off = 32; off; off >>= 1) mx = fmaxf(mx, __shfl_xor(mx, off, 64));
        if ((tid & 63) == 0) red[tid >> 6] = mx;
        __syncthreads();
        mx = fmaxf(fmaxf(red[0], red[1]), fmaxf(red[2], red[3]));
        float sum = 0.f;
#pragma unroll
        for (int i = 0; i < N; i++) { vals[i] = __expf(vals[i] - mx); sum += vals[i]; }
        for (int off = 32; off; off >>= 1) sum += __shfl_xor(sum, off, 64);
        if ((tid & 63) == 0) red2[tid >> 6] = sum;
        __syncthreads();
        const float inv = 1.f / (red2[0] + red2[1] + red2[2] + red2[3]);
#pragma unroll
        for (int i = 0; i < N; i++) {
            const float w = vals[i] * inv;
            p[tid + (i << 8)] = (bf16)w;
            macc[i] += w;
        }
    }
    float* ao = att + ((size_t)b * Lq + l) * S;
#pragma unroll
    for (int i = 0; i < N; i++) ao[tid + (i << 8)] = macc[i] * (1.f / 6.f);
}

// ---------------------------------------------------------------------------
// Split-S PV: Pv[y][l, b*768+h*128+e] = sum over S-half y. Grid (Lq/128, 2, B*H).
// Pipelined.
__global__ __launch_bounds__(256) void attn_pv_sk(
    const bf16* __restrict__ wsm, const bf16* __restrict__ v,
    float* __restrict__ Pv, size_t pstride, int Lq, int S)
{
    __shared__ __align__(16) bf16 As[128][40];
    __shared__ __align__(16) bf16 BsT[128][40];
    const int bh = blockIdx.z;
    const int b = bh / NH, h = bh % NH;
    const int bm = blockIdx.x * 128;
    const int kbase = blockIdx.y * (S >> 1);
    const int tid = threadIdx.x;
    const int wave = tid >> 6, lane = tid & 63;
    const int wm = (wave >> 1) * 64, wn = (wave & 1) * 64;
    const int quad = lane >> 4, m16 = lane & 15;
    const int srow = tid >> 2, scol = (tid & 3) * 8;
    const int kk0 = tid >> 4, e0 = (tid & 15) * 8;
    f32x4 acc[4][4] = {};
    const bf16* wbase = wsm + (size_t)(bh * Lq + bm) * S + kbase;
    const size_t vb = (size_t)b * D_MODEL + h * HD;
    bf16x8 a0, a1, v0, v1;
    a0 = *(const bf16x8*)(wbase + (size_t)srow * S + scol);
    a1 = *(const bf16x8*)(wbase + (size_t)(srow + 64) * S + scol);
    v0 = *(const bf16x8*)(v + (size_t)(kbase + kk0) * ROWSTRIDE + vb + e0);
    v1 = *(const bf16x8*)(v + (size_t)(kbase + kk0 + 16) * ROWSTRIDE + vb + e0);
    for (int k0 = 0; k0 < (S >> 1); k0 += 32) {
        *(bf16x8*)&As[srow][scol]      = a0;
        *(bf16x8*)&As[srow + 64][scol] = a1;
#pragma unroll
        for (int i = 0; i < 8; i++) { BsT[e0 + i][kk0] = v0[i]; BsT[e0 + i][kk0 + 16] = v1[i]; }
        __syncthreads();
        const int kn = k0 + 32;
        if (kn < (S >> 1)) {
            a0 = *(const bf16x8*)(wbase + (size_t)srow * S + kn + scol);
            a1 = *(const bf16x8*)(wbase + (size_t)(srow + 64) * S + kn + scol);
            v0 = *(const bf16x8*)(v + (size_t)(kbase + kn + kk0) * ROWSTRIDE + vb + e0);
            v1 = *(const bf16x8*)(v + (size_t)(kbase + kn + kk0 + 16) * ROWSTRIDE + vb + e0);
        }
        bf16x8 af[4], bfr[4];
#pragma unroll
        for (int i = 0; i < 4; i++) {
            af[i]  = *(const bf16x8*)&As[wm + i * 16 + m16][quad * 8];
            bfr[i] = *(const bf16x8*)&BsT[wn + i * 16 + m16][quad * 8];
        }
#pragma unroll
        for (int i = 0; i < 4; i++)
#pragma unroll
            for (int j = 0; j < 4; j++)
                acc[i][j] = __builtin_amdgcn_mfma_f32_16x16x32_bf16(af[i], bfr[j], acc[i][j], 0, 0, 0);
        __syncthreads();
    }
    float* out = Pv + blockIdx.y * pstride;
#pragma unroll
    for (int i = 0; i < 4; i++)
#pragma unroll
        for (int j = 0; j < 4; j++)
#pragma unroll
            for (int r = 0; r < 4; r++)
                out[(size_t)(bm + wm + i * 16 + quad * 4 + r) * ROWSTRIDE + vb + wn + j * 16 + m16]
                    = acc[i][j][r];
}

// ---------------------------------------------------------------------------
// out = LN(resid + sum_{p<NP} P[p] + xbias) * g + be.
template <int NP, typename TR, typename TO>
__global__ __launch_bounds__(256) void add_ln_p(
    const TR* __restrict__ resid, const float* __restrict__ P, size_t pstride,
    const float* __restrict__ xbias,
    const float* __restrict__ g, const float* __restrict__ be, TO* __restrict__ out)
{
    const size_t base = (size_t)blockIdx.x * D_MODEL;
    const int tid = threadIdx.x;
    float v[3];
#pragma unroll
    for (int i = 0; i < 3; i++) {
        const int c = tid + (i << 8);
        float x = xbias[c];
#pragma unroll
        for (int p = 0; p < NP; p++) x += P[p * pstride + base + c];
        v[i] = (float)resid[base + c] + x;
    }
    float s = v[0] + v[1] + v[2];
    float s2 = v[0] * v[0] + v[1] * v[1] + v[2] * v[2];
    for (int off = 32; off; off >>= 1) { s += __shfl_xor(s, off, 64); s2 += __shfl_xor(s2, off, 64); }
    __shared__ float rs[4], rs2[4];
    if ((tid & 63) == 0) { rs[tid >> 6] = s; rs2[tid >> 6] = s2; }
    __syncthreads();
    s = rs[0] + rs[1] + rs[2] + rs[3];
    s2 = rs2[0] + rs2[1] + rs2[2] + rs2[3];
    const float mean = s * (1.f / 768.f);
    const float var = s2 * (1.f / 768.f) - mean * mean;
    const float inv = rsqrtf(var + 1e-5f);
#pragma unroll
    for (int i = 0; i < 3; i++) {
        const int c = tid + (i << 8);
        out[base + c] = (TO)((v[i] - mean) * inv * g[c] + be[c]);
    }
}

// ---------------------------------------------------------------------------
extern "C" void kernel_launch(void* const* d_in, const int* in_sizes, int n_in,
                              void* d_out, int out_size, void* d_ws, size_t ws_size,
                              hipStream_t stream)
{
    const float* tgt        = (const float*)d_in[0];
    const float* memory     = (const float*)d_in[1];
    const float* tgt_pos    = (const float*)d_in[2];
    const float* memory_pos = (const float*)d_in[3];
    const float* tgt_pos2   = (const float*)d_in[4];
    const float *sa_w[6], *sa_b[6], *ca_w[6], *ca_b[6];
    for (int i = 0; i < 6; i++) {
        sa_w[i] = (const float*)d_in[5 + 2 * i];  sa_b[i] = (const float*)d_in[6 + 2 * i];
        ca_w[i] = (const float*)d_in[17 + 2 * i]; ca_b[i] = (const float*)d_in[18 + 2 * i];
    }
    const float* ff1_w = (const float*)d_in[29]; const float* ff1_b = (const float*)d_in[30];
    const float* ff2_w = (const float*)d_in[31]; const float* ff2_b = (const float*)d_in[32];
    const float* ln_g[3] = {(const float*)d_in[33], (const float*)d_in[35], (const float*)d_in[37]};
    const float* ln_b[3] = {(const float*)d_in[34], (const float*)d_in[36], (const float*)d_in[38]};

    // ---- workspace (106,954,752 B) ----
    char* ws = (char*)d_ws;
    bf16* qc  = (bf16*)(ws);                // [0, 6291456)
    bf16* qp  = (bf16*)(ws + 6291456);      // [6291456, 12582912)
    bf16* kc  = (bf16*)(ws + 12582912);     // [12582912, 25165824)
    bf16* kp  = (bf16*)(ws + 25165824);     // [25165824, 37748736)
    bf16* vv  = (bf16*)(ws + 37748736);     // [37748736, 50331648)
    bf16* t1  = (bf16*)(ws + 50331648);     // [50331648, 56623104)
    bf16* sc  = (bf16*)(ws + 56623104);     // [56623104, 106954752) 50.33 MB
    // fp32 partial regions (all liveness-checked vs the launch sequence):
    const size_t PSTRIDE = 3145728;  // floats per 12.58 MB slice
    float* pv_sa = (float*)(ws + 81788928);  // sc_hi: SA PV pair (sc_lo = SA scores live)
    float* pv_ca = (float*)(ws + 12582912);  // kc+kp: dead after CA scores
    float* op    = (float*)(ws + 56623104);  // sc_lo: out-proj pair (both phases)
    float* fp    = (float*)(ws + 56623104);  // FFN2 4-slice = full sc (dead)
    bf16*  tca   = kc;                       // Pv_ca dead after CA out-proj
    bf16*  ffh   = kp;                       // 16.78 MB over dead kp+vv

    float* out_t    = (float*)d_out;        // (L,B,D)
    float* out_att  = out_t + 3145728;      // (B,L,S)
    float* out_satt = out_att + 4194304;    // (B,L,L)

    const dim3 blk(256);
    const float SCALE = 0.0625f;

    // ---- self attention ----
    {
        Jobs5 J;
        J.j[0] = {tgt_pos, nullptr, sa_w[0], sa_b[0], qc, 0, 0};
        J.j[1] = {tgt,     nullptr, sa_w[1], sa_b[1], qp, 0, 0};
        J.j[2] = {tgt_pos, nullptr, sa_w[2], sa_b[2], kc, 0, 0};
        J.j[3] = {tgt,     nullptr, sa_w[3], sa_b[3], kp, 0, 0};
        J.j[4] = {tgt,     nullptr, sa_w[4], sa_b[4], vv, 0, 0};
        gemm_jobs<<<dim3(6, 32, 5), blk, 0, stream>>>(J, 768, 768, 768, 768);
    }
    attn_scores<<<dim3(4, 4, 48), blk, 0, stream>>>(qc, qp, kc, kp, sc, 512, 512, SCALE);
    softmax_mean<2><<<dim3(512, 8), blk, 0, stream>>>(sc, out_satt, 512);
    attn_pv_sk<<<dim3(4, 2, 48), blk, 0, stream>>>(sc, vv, pv_sa, PSTRIDE, 512, 512);
    gemm_sk<3><<<dim3(6, 32, 2), blk, 0, stream>>>(pv_sa, pv_sa + PSTRIDE, 768,
                                                   sa_w[5], 768, op, PSTRIDE, 768, 384);
    add_ln_p<2, float, bf16><<<dim3(4096), blk, 0, stream>>>(tgt, op, PSTRIDE, sa_b[5],
                                                             ln_g[0], ln_b[0], t1);

    // ---- cross attention ----
    {
        Jobs5 J = {};
        J.j[0] = {tgt_pos, nullptr,  ca_w[0], ca_b[0], qc, 0, 0};
        J.j[1] = {t1,      tgt_pos2, ca_w[1], ca_b[1], qp, 2, 0};
        gemm_jobs<<<dim3(6, 32, 2), blk, 0, stream>>>(J, 768, 768, 768, 768);
    }
    {
        Jobs5 J = {};
        J.j[0] = {memory,     nullptr, ca_w[2], ca_b[2], kc, 0, 0};
        J.j[1] = {memory_pos, nullptr, ca_w[3], ca_b[3], kp, 0, 0};
        J.j[2] = {memory_pos, nullptr, ca_w[4], ca_b[4], vv, 0, 0};
        gemm_jobs<<<dim3(6, 64, 3), blk, 0, stream>>>(J, 768, 768, 768, 768);
    }
    attn_scores<<<dim3(8, 4, 48), blk, 0, stream>>>(qc, qp, kc, kp, sc, 512, 1024, SCALE);
    softmax_mean<4><<<dim3(512, 8), blk, 0, stream>>>(sc, out_att, 512);
    attn_pv_sk<<<dim3(4, 2, 48), blk, 0, stream>>>(sc, vv, pv_ca, PSTRIDE, 512, 1024);
    gemm_sk<3><<<dim3(6, 32, 2), blk, 0, stream>>>(pv_ca, pv_ca + PSTRIDE, 768,
                                                   ca_w[5], 768, op, PSTRIDE, 768, 384);
    add_ln_p<2, bf16, bf16><<<dim3(4096), blk, 0, stream>>>(t1, op, PSTRIDE, ca_b[5],
                                                            ln_g[1], ln_b[1], tca);

    // ---- FFN ----
    {
        Jobs5 J = {};
        J.j[0] = {tca, nullptr, ff1_w, ff1_b, ffh, 1, 1};
        gemm_jobs<<<dim3(16, 32, 1), blk, 0, stream>>>(J, 768, 768, 2048, 768);
    }
    gemm_sk<1><<<dim3(6, 32, 4), blk, 0, stream>>>(ffh, nullptr, 2048,
                                                   ff2_w, 2048, fp, PSTRIDE, 768, 512);
    add_ln_p<4, bf16, float><<<dim3(4096), blk, 0, stream>>>(tca, fp, PSTRIDE, ff2_b,
                                                             ln_g[2], ln_b[2], out_t);
}

// Round 5
// 742.908 us; speedup vs baseline: 1.0508x; 1.0508x over previous
//
#include <hip/hip_runtime.h>

// Conditional-DETR decoder layer, MI355X gfx950.
// R9 green @ 780.7 us. CA kv gemm_jobs: 121 us, FETCH 235 MB (unique ~57 MB),
// HBM 29%, MfmaUtil 9% (= pure MFMA floor) -> L2-refetch bound: consecutive
// blocks round-robin over 8 XCD-private L2s, so W-tiles (shared by 64 y-blocks)
// and A-row-blocks (shared by 6 x-blocks) are re-fetched per XCD.
// R10: chunked bijective XCD swizzle (T1) in all 5 MFMA kernels.
// tile = (flat%8)*(n/8) + flat/8, x-fastest decode -> each XCD walks a
// contiguous y-range with all x, keeping its W set L2-resident and streaming
// A-row-blocks once. Bit-identical numerics (same tiles, same in-block order).
// Predict: CA kv FETCH 235->~100 MB, dur 121->~60 us; total 780->~620 us.
// R11/R12: unchanged resubmits — benches died on container acquisition (infra).
// Considered+rejected bundling an LDS bank fix: regime gate (m230/m233) says
// conflict fixes are timing-null in 2-phase schedules (stage+barrier is the
// critical path), and it would contaminate this round's FETCH/dur attribution.

typedef __bf16 bf16;
typedef __attribute__((ext_vector_type(8))) __bf16 bf16x8;
typedef __attribute__((ext_vector_type(4))) float f32x4;

#define D_MODEL 768
#define NH 6
#define HD 128
#define ROWSTRIDE (8 * D_MODEL)  // 6144 (B*D)

// XCD-aware chunked swizzle: requires gridDim.x*y*z % 8 == 0 (all our grids).
__device__ inline void swz_xyz(int& x, int& y, int& z) {
    const int nx = gridDim.x, ny = gridDim.y;
    const int n = nx * ny * gridDim.z;
    const int flat = blockIdx.x + nx * (blockIdx.y + ny * blockIdx.z);
    const int t = (flat & 7) * (n >> 3) + (flat >> 3);
    x = t % nx;
    const int r = t / nx;
    y = r % ny;
    z = r / ny;
}

// 8-elem staging loaders -> bf16x8
__device__ inline bf16x8 ld8f(const float* p) {
    f32x4 a = *(const f32x4*)p, b = *(const f32x4*)(p + 4);
    bf16x8 r;
#pragma unroll
    for (int i = 0; i < 4; i++) { r[i] = (bf16)a[i]; r[i + 4] = (bf16)b[i]; }
    return r;
}
__device__ inline bf16x8 ld8b(const bf16* p) { return *(const bf16x8*)p; }
__device__ inline bf16x8 ld8bf(const bf16* p, const float* q) {  // bf16 + f32
    bf16x8 x = *(const bf16x8*)p;
    f32x4 a = *(const f32x4*)q, b = *(const f32x4*)(q + 4);
    bf16x8 r;
#pragma unroll
    for (int i = 0; i < 4; i++) { r[i] = (bf16)((float)x[i] + a[i]); r[i + 4] = (bf16)((float)x[i + 4] + b[i]); }
    return r;
}
__device__ inline bf16x8 ld8ff(const float* p, const float* q) {  // f32 + f32
    f32x4 a = *(const f32x4*)p, b = *(const f32x4*)(p + 4);
    f32x4 c = *(const f32x4*)q, d = *(const f32x4*)(q + 4);
    bf16x8 r;
#pragma unroll
    for (int i = 0; i < 4; i++) { r[i] = (bf16)(a[i] + c[i]); r[i + 4] = (bf16)(b[i] + d[i]); }
    return r;
}

// ---------------------------------------------------------------------------
// Multi-job GEMM: per z-slice job: C[M,N] = A[M,K] * W[N,K]^T + bias.
// aty: 0 = A fp32, 1 = A bf16, 2 = A bf16 + A2 fp32 (summed).
// 128x128 tile, 256 thr = 4 waves (2x2), 4x4 MFMA 16x16x32 per wave.
// K-loop software-pipelined: tile k+1 global->reg issue before tile k MFMAs.
struct Job { const void* A; const void* A2; const float* W; const float* bias;
             bf16* C; int aty; int relu; };
struct Jobs5 { Job j[5]; };

__device__ inline void load_a(const Job& jb, size_t off, int k0, bf16x8& r) {
    if (jb.aty == 0)      r = ld8f((const float*)jb.A + off + k0);
    else if (jb.aty == 1) r = ld8b((const bf16*)jb.A + off + k0);
    else                  r = ld8bf((const bf16*)jb.A + off + k0,
                                    (const float*)jb.A2 + off + k0);
}

__global__ __launch_bounds__(256) void gemm_jobs(
    Jobs5 jobs, int lda, int ldw, int ldc, int K)
{
    __shared__ __align__(16) bf16 As[128][40];
    __shared__ __align__(16) bf16 Bs[128][40];
    int bx, by, bz;
    swz_xyz(bx, by, bz);
    const Job jb = jobs.j[bz];
    const int bm = by * 128, bn = bx * 128;
    const int tid = threadIdx.x;
    const int wave = tid >> 6, lane = tid & 63;
    const int wm = (wave >> 1) * 64, wn = (wave & 1) * 64;
    const int quad = lane >> 4, m16 = lane & 15;
    const int srow = tid >> 2, scol = (tid & 3) * 8;
    f32x4 acc[4][4] = {};
    const size_t aoff0 = (size_t)(bm + srow) * lda + scol;
    const size_t aoff1 = aoff0 + (size_t)64 * lda;
    const size_t woff0 = (size_t)(bn + srow) * ldw + scol;
    const size_t woff1 = woff0 + (size_t)64 * ldw;
    bf16x8 a0, a1, b0, b1;
    load_a(jb, aoff0, 0, a0);
    load_a(jb, aoff1, 0, a1);
    b0 = ld8f(jb.W + woff0);
    b1 = ld8f(jb.W + woff1);
    for (int k0 = 0; k0 < K; k0 += 32) {
        *(bf16x8*)&As[srow][scol]      = a0;
        *(bf16x8*)&As[srow + 64][scol] = a1;
        *(bf16x8*)&Bs[srow][scol]      = b0;
        *(bf16x8*)&Bs[srow + 64][scol] = b1;
        __syncthreads();
        const int kn = k0 + 32;
        if (kn < K) {
            load_a(jb, aoff0, kn, a0);
            load_a(jb, aoff1, kn, a1);
            b0 = ld8f(jb.W + woff0 + kn);
            b1 = ld8f(jb.W + woff1 + kn);
        }
        bf16x8 af[4], bfr[4];
#pragma unroll
        for (int i = 0; i < 4; i++) {
            af[i]  = *(const bf16x8*)&As[wm + i * 16 + m16][quad * 8];
            bfr[i] = *(const bf16x8*)&Bs[wn + i * 16 + m16][quad * 8];
        }
#pragma unroll
        for (int i = 0; i < 4; i++)
#pragma unroll
            for (int j = 0; j < 4; j++)
                acc[i][j] = __builtin_amdgcn_mfma_f32_16x16x32_bf16(af[i], bfr[j], acc[i][j], 0, 0, 0);
        __syncthreads();
    }
#pragma unroll
    for (int j = 0; j < 4; j++) {
        const int col = bn + wn + j * 16 + m16;
        const float bv = jb.bias[col];
#pragma unroll
        for (int i = 0; i < 4; i++)
#pragma unroll
            for (int r = 0; r < 4; r++) {
                const int row = bm + wm + i * 16 + quad * 4 + r;
                float val = acc[i][j][r] + bv;
                if (jb.relu) val = fmaxf(val, 0.f);
                jb.C[(size_t)row * ldc + col] = (bf16)val;
            }
    }
}

// ---------------------------------------------------------------------------
// Split-K GEMM: z = K-slice; fp32 partial out (no bias — folded into add_ln).
// ATY 1 = bf16 A; ATY 3 = fp32+fp32 dual A (PV partial pair). Pipelined.
template <int ATY>
__global__ __launch_bounds__(256) void gemm_sk(
    const void* __restrict__ A, const void* __restrict__ A2, int lda,
    const float* __restrict__ W, int ldw,
    float* __restrict__ Cp, size_t cstride, int ldc, int Ks)
{
    __shared__ __align__(16) bf16 As[128][40];
    __shared__ __align__(16) bf16 Bs[128][40];
    int bx, by, bz;
    swz_xyz(bx, by, bz);
    const int bm = by * 128, bn = bx * 128;
    const int kbase = bz * Ks;
    const int tid = threadIdx.x;
    const int wave = tid >> 6, lane = tid & 63;
    const int wm = (wave >> 1) * 64, wn = (wave & 1) * 64;
    const int quad = lane >> 4, m16 = lane & 15;
    const int srow = tid >> 2, scol = (tid & 3) * 8;
    f32x4 acc[4][4] = {};
    const size_t aoff0 = (size_t)(bm + srow) * lda + kbase + scol;
    const size_t aoff1 = aoff0 + (size_t)64 * lda;
    const size_t woff0 = (size_t)(bn + srow) * ldw + kbase + scol;
    const size_t woff1 = woff0 + (size_t)64 * ldw;
    bf16x8 a0, a1, b0, b1;
    if (ATY == 1) {
        a0 = ld8b((const bf16*)A + aoff0);
        a1 = ld8b((const bf16*)A + aoff1);
    } else {
        a0 = ld8ff((const float*)A + aoff0, (const float*)A2 + aoff0);
        a1 = ld8ff((const float*)A + aoff1, (const float*)A2 + aoff1);
    }
    b0 = ld8f(W + woff0);
    b1 = ld8f(W + woff1);
    for (int k0 = 0; k0 < Ks; k0 += 32) {
        *(bf16x8*)&As[srow][scol]      = a0;
        *(bf16x8*)&As[srow + 64][scol] = a1;
        *(bf16x8*)&Bs[srow][scol]      = b0;
        *(bf16x8*)&Bs[srow + 64][scol] = b1;
        __syncthreads();
        const int kn = k0 + 32;
        if (kn < Ks) {
            if (ATY == 1) {
                a0 = ld8b((const bf16*)A + aoff0 + kn);
                a1 = ld8b((const bf16*)A + aoff1 + kn);
            } else {
                a0 = ld8ff((const float*)A + aoff0 + kn, (const float*)A2 + aoff0 + kn);
                a1 = ld8ff((const float*)A + aoff1 + kn, (const float*)A2 + aoff1 + kn);
            }
            b0 = ld8f(W + woff0 + kn);
            b1 = ld8f(W + woff1 + kn);
        }
        bf16x8 af[4], bfr[4];
#pragma unroll
        for (int i = 0; i < 4; i++) {
            af[i]  = *(const bf16x8*)&As[wm + i * 16 + m16][quad * 8];
            bfr[i] = *(const bf16x8*)&Bs[wn + i * 16 + m16][quad * 8];
        }
#pragma unroll
        for (int i = 0; i < 4; i++)
#pragma unroll
            for (int j = 0; j < 4; j++)
                acc[i][j] = __builtin_amdgcn_mfma_f32_16x16x32_bf16(af[i], bfr[j], acc[i][j], 0, 0, 0);
        __syncthreads();
    }
    float* out = Cp + (size_t)bz * cstride;
#pragma unroll
    for (int j = 0; j < 4; j++) {
        const int col = bn + wn + j * 16 + m16;
#pragma unroll
        for (int i = 0; i < 4; i++)
#pragma unroll
            for (int r = 0; r < 4; r++) {
                const int row = bm + wm + i * 16 + quad * 4 + r;
                out[(size_t)row * ldc + col] = acc[i][j][r];
            }
    }
}

// ---------------------------------------------------------------------------
// scores[bh,l,s] = scale*(qc.kc + qp.kp), K=256. Grid (S/128, Lq/128, B*H).
// Pipelined like the GEMMs.
__global__ __launch_bounds__(256) void attn_scores(
    const bf16* __restrict__ qc, const bf16* __restrict__ qp,
    const bf16* __restrict__ kc, const bf16* __restrict__ kp,
    bf16* __restrict__ scores, int Lq, int S, float scale)
{
    __shared__ __align__(16) bf16 As[128][40];
    __shared__ __align__(16) bf16 Bs[128][40];
    int bx, by, bz;
    swz_xyz(bx, by, bz);
    const int bh = bz;
    const int b = bh / NH, h = bh % NH;
    const int bm = by * 128, bn = bx * 128;
    const int tid = threadIdx.x;
    const int wave = tid >> 6, lane = tid & 63;
    const int wm = (wave >> 1) * 64, wn = (wave & 1) * 64;
    const int quad = lane >> 4, m16 = lane & 15;
    const int srow = tid >> 2, scol = (tid & 3) * 8;
    f32x4 acc[4][4] = {};
    const size_t hb = (size_t)b * D_MODEL + h * HD;
    bf16x8 a0, a1, b0, b1;
    a0 = *(const bf16x8*)(qc + (size_t)(bm + srow) * ROWSTRIDE + hb + scol);
    a1 = *(const bf16x8*)(qc + (size_t)(bm + srow + 64) * ROWSTRIDE + hb + scol);
    b0 = *(const bf16x8*)(kc + (size_t)(bn + srow) * ROWSTRIDE + hb + scol);
    b1 = *(const bf16x8*)(kc + (size_t)(bn + srow + 64) * ROWSTRIDE + hb + scol);
    for (int k0 = 0; k0 < 256; k0 += 32) {
        *(bf16x8*)&As[srow][scol]      = a0;
        *(bf16x8*)&As[srow + 64][scol] = a1;
        *(bf16x8*)&Bs[srow][scol]      = b0;
        *(bf16x8*)&Bs[srow + 64][scol] = b1;
        __syncthreads();
        const int kn = k0 + 32;
        if (kn < 256) {
            const bf16* qsrc = (kn < 128) ? qc : qp;
            const bf16* ksrc = (kn < 128) ? kc : kp;
            const int kcol = (kn & 127) + scol;
            a0 = *(const bf16x8*)(qsrc + (size_t)(bm + srow) * ROWSTRIDE + hb + kcol);
            a1 = *(const bf16x8*)(qsrc + (size_t)(bm + srow + 64) * ROWSTRIDE + hb + kcol);
            b0 = *(const bf16x8*)(ksrc + (size_t)(bn + srow) * ROWSTRIDE + hb + kcol);
            b1 = *(const bf16x8*)(ksrc + (size_t)(bn + srow + 64) * ROWSTRIDE + hb + kcol);
        }
        bf16x8 af[4], bfr[4];
#pragma unroll
        for (int i = 0; i < 4; i++) {
            af[i]  = *(const bf16x8*)&As[wm + i * 16 + m16][quad * 8];
            bfr[i] = *(const bf16x8*)&Bs[wn + i * 16 + m16][quad * 8];
        }
#pragma unroll
        for (int i = 0; i < 4; i++)
#pragma unroll
            for (int j = 0; j < 4; j++)
                acc[i][j] = __builtin_amdgcn_mfma_f32_16x16x32_bf16(af[i], bfr[j], acc[i][j], 0, 0, 0);
        __syncthreads();
    }
    bf16* sb = scores + (size_t)bh * Lq * S;
#pragma unroll
    for (int i = 0; i < 4; i++)
#pragma unroll
        for (int j = 0; j < 4; j++)
#pragma unroll
            for (int r = 0; r < 4; r++)
                sb[(size_t)(bm + wm + i * 16 + quad * 4 + r) * S + bn + wn + j * 16 + m16]
                    = (bf16)(acc[i][j][r] * scale);
}

// ---------------------------------------------------------------------------
// Fused softmax + head-mean. One block per (b,l): all NH=6 head rows.
// N = S/256 elems per thread per row. Writes normalized rows back (bf16) and
// the head-averaged row (fp32) from pre-rounding values.
template <int N>
__global__ __launch_bounds__(256) void softmax_mean(
    bf16* __restrict__ scores, float* __restrict__ att, int Lq)
{
    const int S = N << 8;
    const int l = blockIdx.x, b = blockIdx.y;
    const int tid = threadIdx.x;
    __shared__ float red[4], red2[4];
    float macc[N];
#pragma unroll
    for (int i = 0; i < N; i++) macc[i] = 0.f;
    for (int h = 0; h < NH; h++) {
        bf16* p = scores + ((size_t)(b * NH + h) * Lq + l) * S;
        float vals[N];
        float mx = -1e30f;
#pragma unroll
        for (int i = 0; i < N; i++) { vals[i] = (float)p[tid + (i << 8)]; mx = fmaxf(mx, vals[i]); }
        for (int off = 32; off; off >>= 1) mx = fmaxf(mx, __shfl_xor(mx, off, 64));
        if ((tid & 63) == 0) red[tid >> 6] = mx;
        __syncthreads();
        mx = fmaxf(fmaxf(red[0], red[1]), fmaxf(red[2], red[3]));
        float sum = 0.f;
#pragma unroll
        for (int i = 0; i < N; i++) { vals[i] = __expf(vals[i] - mx); sum += vals[i]; }
        for (int off = 32; off; off >>= 1) sum += __shfl_xor(sum, off, 64);
        if ((tid & 63) == 0) red2[tid >> 6] = sum;
        __syncthreads();
        const float inv = 1.f / (red2[0] + red2[1] + red2[2] + red2[3]);
#pragma unroll
        for (int i = 0; i < N; i++) {
            const float w = vals[i] * inv;
            p[tid + (i << 8)] = (bf16)w;
            macc[i] += w;
        }
    }
    float* ao = att + ((size_t)b * Lq + l) * S;
#pragma unroll
    for (int i = 0; i < N; i++) ao[tid + (i << 8)] = macc[i] * (1.f / 6.f);
}

// ---------------------------------------------------------------------------
// Split-S PV: Pv[y][l, b*768+h*128+e] = sum over S-half y. Grid (Lq/128, 2, B*H).
// Pipelined.
__global__ __launch_bounds__(256) void attn_pv_sk(
    const bf16* __restrict__ wsm, const bf16* __restrict__ v,
    float* __restrict__ Pv, size_t pstride, int Lq, int S)
{
    __shared__ __align__(16) bf16 As[128][40];
    __shared__ __align__(16) bf16 BsT[128][40];
    int bx, by, bz;
    swz_xyz(bx, by, bz);
    const int bh = bz;
    const int b = bh / NH, h = bh % NH;
    const int bm = bx * 128;
    const int kbase = by * (S >> 1);
    const int tid = threadIdx.x;
    const int wave = tid >> 6, lane = tid & 63;
    const int wm = (wave >> 1) * 64, wn = (wave & 1) * 64;
    const int quad = lane >> 4, m16 = lane & 15;
    const int srow = tid >> 2, scol = (tid & 3) * 8;
    const int kk0 = tid >> 4, e0 = (tid & 15) * 8;
    f32x4 acc[4][4] = {};
    const bf16* wbase = wsm + (size_t)(bh * Lq + bm) * S + kbase;
    const size_t vb = (size_t)b * D_MODEL + h * HD;
    bf16x8 a0, a1, v0, v1;
    a0 = *(const bf16x8*)(wbase + (size_t)srow * S + scol);
    a1 = *(const bf16x8*)(wbase + (size_t)(srow + 64) * S + scol);
    v0 = *(const bf16x8*)(v + (size_t)(kbase + kk0) * ROWSTRIDE + vb + e0);
    v1 = *(const bf16x8*)(v + (size_t)(kbase + kk0 + 16) * ROWSTRIDE + vb + e0);
    for (int k0 = 0; k0 < (S >> 1); k0 += 32) {
        *(bf16x8*)&As[srow][scol]      = a0;
        *(bf16x8*)&As[srow + 64][scol] = a1;
#pragma unroll
        for (int i = 0; i < 8; i++) { BsT[e0 + i][kk0] = v0[i]; BsT[e0 + i][kk0 + 16] = v1[i]; }
        __syncthreads();
        const int kn = k0 + 32;
        if (kn < (S >> 1)) {
            a0 = *(const bf16x8*)(wbase + (size_t)srow * S + kn + scol);
            a1 = *(const bf16x8*)(wbase + (size_t)(srow + 64) * S + kn + scol);
            v0 = *(const bf16x8*)(v + (size_t)(kbase + kn + kk0) * ROWSTRIDE + vb + e0);
            v1 = *(const bf16x8*)(v + (size_t)(kbase + kn + kk0 + 16) * ROWSTRIDE + vb + e0);
        }
        bf16x8 af[4], bfr[4];
#pragma unroll
        for (int i = 0; i < 4; i++) {
            af[i]  = *(const bf16x8*)&As[wm + i * 16 + m16][quad * 8];
            bfr[i] = *(const bf16x8*)&BsT[wn + i * 16 + m16][quad * 8];
        }
#pragma unroll
        for (int i = 0; i < 4; i++)
#pragma unroll
            for (int j = 0; j < 4; j++)
                acc[i][j] = __builtin_amdgcn_mfma_f32_16x16x32_bf16(af[i], bfr[j], acc[i][j], 0, 0, 0);
        __syncthreads();
    }
    float* out = Pv + by * pstride;
#pragma unroll
    for (int i = 0; i < 4; i++)
#pragma unroll
        for (int j = 0; j < 4; j++)
#pragma unroll
            for (int r = 0; r < 4; r++)
                out[(size_t)(bm + wm + i * 16 + quad * 4 + r) * ROWSTRIDE + vb + wn + j * 16 + m16]
                    = acc[i][j][r];
}

// ---------------------------------------------------------------------------
// out = LN(resid + sum_{p<NP} P[p] + xbias) * g + be.
template <int NP, typename TR, typename TO>
__global__ __launch_bounds__(256) void add_ln_p(
    const TR* __restrict__ resid, const float* __restrict__ P, size_t pstride,
    const float* __restrict__ xbias,
    const float* __restrict__ g, const float* __restrict__ be, TO* __restrict__ out)
{
    const size_t base = (size_t)blockIdx.x * D_MODEL;
    const int tid = threadIdx.x;
    float v[3];
#pragma unroll
    for (int i = 0; i < 3; i++) {
        const int c = tid + (i << 8);
        float x = xbias[c];
#pragma unroll
        for (int p = 0; p < NP; p++) x += P[p * pstride + base + c];
        v[i] = (float)resid[base + c] + x;
    }
    float s = v[0] + v[1] + v[2];
    float s2 = v[0] * v[0] + v[1] * v[1] + v[2] * v[2];
    for (int off = 32; off; off >>= 1) { s += __shfl_xor(s, off, 64); s2 += __shfl_xor(s2, off, 64); }
    __shared__ float rs[4], rs2[4];
    if ((tid & 63) == 0) { rs[tid >> 6] = s; rs2[tid >> 6] = s2; }
    __syncthreads();
    s = rs[0] + rs[1] + rs[2] + rs[3];
    s2 = rs2[0] + rs2[1] + rs2[2] + rs2[3];
    const float mean = s * (1.f / 768.f);
    const float var = s2 * (1.f / 768.f) - mean * mean;
    const float inv = rsqrtf(var + 1e-5f);
#pragma unroll
    for (int i = 0; i < 3; i++) {
        const int c = tid + (i << 8);
        out[base + c] = (TO)((v[i] - mean) * inv * g[c] + be[c]);
    }
}

// ---------------------------------------------------------------------------
extern "C" void kernel_launch(void* const* d_in, const int* in_sizes, int n_in,
                              void* d_out, int out_size, void* d_ws, size_t ws_size,
                              hipStream_t stream)
{
    const float* tgt        = (const float*)d_in[0];
    const float* memory     = (const float*)d_in[1];
    const float* tgt_pos    = (const float*)d_in[2];
    const float* memory_pos = (const float*)d_in[3];
    const float* tgt_pos2   = (const float*)d_in[4];
    const float *sa_w[6], *sa_b[6], *ca_w[6], *ca_b[6];
    for (int i = 0; i < 6; i++) {
        sa_w[i] = (const float*)d_in[5 + 2 * i];  sa_b[i] = (const float*)d_in[6 + 2 * i];
        ca_w[i] = (const float*)d_in[17 + 2 * i]; ca_b[i] = (const float*)d_in[18 + 2 * i];
    }
    const float* ff1_w = (const float*)d_in[29]; const float* ff1_b = (const float*)d_in[30];
    const float* ff2_w = (const float*)d_in[31]; const float* ff2_b = (const float*)d_in[32];
    const float* ln_g[3] = {(const float*)d_in[33], (const float*)d_in[35], (const float*)d_in[37]};
    const float* ln_b[3] = {(const float*)d_in[34], (const float*)d_in[36], (const float*)d_in[38]};

    // ---- workspace (106,954,752 B) ----
    char* ws = (char*)d_ws;
    bf16* qc  = (bf16*)(ws);                // [0, 6291456)
    bf16* qp  = (bf16*)(ws + 6291456);      // [6291456, 12582912)
    bf16* kc  = (bf16*)(ws + 12582912);     // [12582912, 25165824)
    bf16* kp  = (bf16*)(ws + 25165824);     // [25165824, 37748736)
    bf16* vv  = (bf16*)(ws + 37748736);     // [37748736, 50331648)
    bf16* t1  = (bf16*)(ws + 50331648);     // [50331648, 56623104)
    bf16* sc  = (bf16*)(ws + 56623104);     // [56623104, 106954752) 50.33 MB
    // fp32 partial regions (all liveness-checked vs the launch sequence):
    const size_t PSTRIDE = 3145728;  // floats per 12.58 MB slice
    float* pv_sa = (float*)(ws + 81788928);  // sc_hi: SA PV pair (sc_lo = SA scores live)
    float* pv_ca = (float*)(ws + 12582912);  // kc+kp: dead after CA scores
    float* op    = (float*)(ws + 56623104);  // sc_lo: out-proj pair (both phases)
    float* fp    = (float*)(ws + 56623104);  // FFN2 4-slice = full sc (dead)
    bf16*  tca   = kc;                       // Pv_ca dead after CA out-proj
    bf16*  ffh   = kp;                       // 16.78 MB over dead kp+vv

    float* out_t    = (float*)d_out;        // (L,B,D)
    float* out_att  = out_t + 3145728;      // (B,L,S)
    float* out_satt = out_att + 4194304;    // (B,L,L)

    const dim3 blk(256);
    const float SCALE = 0.0625f;

    // ---- self attention ----
    {
        Jobs5 J;
        J.j[0] = {tgt_pos, nullptr, sa_w[0], sa_b[0], qc, 0, 0};
        J.j[1] = {tgt,     nullptr, sa_w[1], sa_b[1], qp, 0, 0};
        J.j[2] = {tgt_pos, nullptr, sa_w[2], sa_b[2], kc, 0, 0};
        J.j[3] = {tgt,     nullptr, sa_w[3], sa_b[3], kp, 0, 0};
        J.j[4] = {tgt,     nullptr, sa_w[4], sa_b[4], vv, 0, 0};
        gemm_jobs<<<dim3(6, 32, 5), blk, 0, stream>>>(J, 768, 768, 768, 768);
    }
    attn_scores<<<dim3(4, 4, 48), blk, 0, stream>>>(qc, qp, kc, kp, sc, 512, 512, SCALE);
    softmax_mean<2><<<dim3(512, 8), blk, 0, stream>>>(sc, out_satt, 512);
    attn_pv_sk<<<dim3(4, 2, 48), blk, 0, stream>>>(sc, vv, pv_sa, PSTRIDE, 512, 512);
    gemm_sk<3><<<dim3(6, 32, 2), blk, 0, stream>>>(pv_sa, pv_sa + PSTRIDE, 768,
                                                   sa_w[5], 768, op, PSTRIDE, 768, 384);
    add_ln_p<2, float, bf16><<<dim3(4096), blk, 0, stream>>>(tgt, op, PSTRIDE, sa_b[5],
                                                             ln_g[0], ln_b[0], t1);

    // ---- cross attention ----
    {
        Jobs5 J = {};
        J.j[0] = {tgt_pos, nullptr,  ca_w[0], ca_b[0], qc, 0, 0};
        J.j[1] = {t1,      tgt_pos2, ca_w[1], ca_b[1], qp, 2, 0};
        gemm_jobs<<<dim3(6, 32, 2), blk, 0, stream>>>(J, 768, 768, 768, 768);
    }
    {
        Jobs5 J = {};
        J.j[0] = {memory,     nullptr, ca_w[2], ca_b[2], kc, 0, 0};
        J.j[1] = {memory_pos, nullptr, ca_w[3], ca_b[3], kp, 0, 0};
        J.j[2] = {memory_pos, nullptr, ca_w[4], ca_b[4], vv, 0, 0};
        gemm_jobs<<<dim3(6, 64, 3), blk, 0, stream>>>(J, 768, 768, 768, 768);
    }
    attn_scores<<<dim3(8, 4, 48), blk, 0, stream>>>(qc, qp, kc, kp, sc, 512, 1024, SCALE);
    softmax_mean<4><<<dim3(512, 8), blk, 0, stream>>>(sc, out_att, 512);
    attn_pv_sk<<<dim3(4, 2, 48), blk, 0, stream>>>(sc, vv, pv_ca, PSTRIDE, 512, 1024);
    gemm_sk<3><<<dim3(6, 32, 2), blk, 0, stream>>>(pv_ca, pv_ca + PSTRIDE, 768,
                                                   ca_w[5], 768, op, PSTRIDE, 768, 384);
    add_ln_p<2, bf16, bf16><<<dim3(4096), blk, 0, stream>>>(t1, op, PSTRIDE, ca_b[5],
                                                            ln_g[1], ln_b[1], tca);

    // ---- FFN ----
    {
        Jobs5 J = {};
        J.j[0] = {tca, nullptr, ff1_w, ff1_b, ffh, 1, 1};
        gemm_jobs<<<dim3(16, 32, 1), blk, 0, stream>>>(J, 768, 768, 2048, 768);
    }
    gemm_sk<1><<<dim3(6, 32, 4), blk, 0, stream>>>(ffh, nullptr, 2048,
                                                   ff2_w, 2048, fp, PSTRIDE, 768, 512);
    add_ln_p<4, bf16, float><<<dim3(4096), blk, 0, stream>>>(tca, fp, PSTRIDE, ff2_b,
                                                             ln_g[2], ln_b[2], out_t);
}

// Round 6
// 656.622 us; speedup vs baseline: 1.1889x; 1.1314x over previous
//
#include <hip/hip_runtime.h>

// Conditional-DETR decoder layer, MI355X gfx950.
// R10 green @ 742.9 us. Swizzle verified: CA kv FETCH 235->56.5 MB (=unique),
// but dur 121->119 flat; HBM 10.7%, Mfma 9.5%, VALU 9.4%, Occ 24% -> blocks
// internally latency-bound: fp32 reg-staging (load->cvt->LDS) on the critical
// path, ~3 blocks/CU can't hide it.
// R13 (this): global_load_lds(16B) staging (m151: 646->874 TF on this exact
// 128^2 2-barrier structure; m193 +67%):
//  - cvt passes (bit-identical rounding): 8 hot W mats -> bf16 stash in d_out
//    out_t region (free until last kernel); tgt/tgt_pos -> bf16 in dead sc
//    before SA; memory/memory_pos after add_ln1 (sc dead again).
//  - gemm_bb: all-bf16 jobs GEMM, A+W via gload_lds -> linear [128][32] LDS
//    (wave-uniform dest + lane*16), m97 2-barrier loop. SA proj + CA kv.
//  - attn_scores: both tiles gload_lds; attn_pv_sk: A-side only (V transpose
//    scatter stays reg-staged).
//  - CA q (fp32/dual-A), out-projs, FFN unchanged old paths.
// Predict: CA kv 119->~80 us (VALU ~4%, Mfma ~14%), SA proj similar,
// total 743 -> ~620-645. absmax must stay exactly 0.03125.

typedef __bf16 bf16;
typedef __attribute__((ext_vector_type(8))) __bf16 bf16x8;
typedef __attribute__((ext_vector_type(4))) float f32x4;

#define D_MODEL 768
#define NH 6
#define HD 128
#define ROWSTRIDE (8 * D_MODEL)  // 6144 (B*D)

// XCD-aware chunked swizzle: requires gridDim.x*y*z % 8 == 0 (all our grids).
__device__ inline void swz_xyz(int& x, int& y, int& z) {
    const int nx = gridDim.x, ny = gridDim.y;
    const int n = nx * ny * gridDim.z;
    const int flat = blockIdx.x + nx * (blockIdx.y + ny * blockIdx.z);
    const int t = (flat & 7) * (n >> 3) + (flat >> 3);
    x = t % nx;
    const int r = t / nx;
    y = r % ny;
    z = r / ny;
}

// global->LDS direct DMA, 16 B per lane. Dest is wave-uniform base + lane*16.
__device__ __forceinline__ void gld16(const bf16* g, bf16* l) {
    __builtin_amdgcn_global_load_lds(
        (const __attribute__((address_space(1))) unsigned int*)g,
        (__attribute__((address_space(3))) unsigned int*)l, 16, 0, 0);
}

// 8-elem staging loaders -> bf16x8
__device__ inline bf16x8 ld8f(const float* p) {
    f32x4 a = *(const f32x4*)p, b = *(const f32x4*)(p + 4);
    bf16x8 r;
#pragma unroll
    for (int i = 0; i < 4; i++) { r[i] = (bf16)a[i]; r[i + 4] = (bf16)b[i]; }
    return r;
}
__device__ inline bf16x8 ld8b(const bf16* p) { return *(const bf16x8*)p; }
__device__ inline bf16x8 ld8bf(const bf16* p, const float* q) {  // bf16 + f32
    bf16x8 x = *(const bf16x8*)p;
    f32x4 a = *(const f32x4*)q, b = *(const f32x4*)(q + 4);
    bf16x8 r;
#pragma unroll
    for (int i = 0; i < 4; i++) { r[i] = (bf16)((float)x[i] + a[i]); r[i + 4] = (bf16)((float)x[i + 4] + b[i]); }
    return r;
}
__device__ inline bf16x8 ld8ff(const float* p, const float* q) {  // f32 + f32
    f32x4 a = *(const f32x4*)p, b = *(const f32x4*)(p + 4);
    f32x4 c = *(const f32x4*)q, d = *(const f32x4*)(q + 4);
    bf16x8 r;
#pragma unroll
    for (int i = 0; i < 4; i++) { r[i] = (bf16)(a[i] + c[i]); r[i + 4] = (bf16)(b[i] + d[i]); }
    return r;
}

// ---------------------------------------------------------------------------
// Multi-segment fp32 -> bf16 conversion (grid-stride; blockIdx.y = job).
struct CvtJob { const float* src; bf16* dst; int nvec; };
struct CvtJobs { CvtJob j[12]; };

__global__ __launch_bounds__(256) void cvt_multi(CvtJobs jobs)
{
    const CvtJob jb = jobs.j[blockIdx.y];
    const int stride = gridDim.x * 256;
    for (int i = blockIdx.x * 256 + threadIdx.x; i < jb.nvec; i += stride)
        *(bf16x8*)(jb.dst + (size_t)i * 8) = ld8f(jb.src + (size_t)i * 8);
}

// ---------------------------------------------------------------------------
// All-bf16 multi-job GEMM with global_load_lds staging (m97 structure).
// C[M,N] = A[M,K] * W[N,K]^T + bias. Linear LDS [128][32] per operand.
// Per K-step: 8 chunks/tile (16 rows each); wave w DMAs chunks {2w, 2w+1}.
struct JobB { const bf16* A; const bf16* W; const float* bias; bf16* C; int relu; };
struct JobsB { JobB j[5]; };

__global__ __launch_bounds__(256) void gemm_bb(
    JobsB jobs, int lda, int ldw, int ldc, int K)
{
    __shared__ __align__(16) bf16 As[128 * 32];
    __shared__ __align__(16) bf16 Bs[128 * 32];
    int bx, by, bz;
    swz_xyz(bx, by, bz);
    const JobB jb = jobs.j[bz];
    const int bm = by * 128, bn = bx * 128;
    const int tid = threadIdx.x;
    const int wave = tid >> 6, lane = tid & 63;
    const int wm = (wave >> 1) * 64, wn = (wave & 1) * 64;
    const int quad = lane >> 4, m16 = lane & 15;
    const int crow = lane >> 2, ccol = (lane & 3) * 8;  // within-chunk src coords
    const bf16* a0 = jb.A + (size_t)(bm + wave * 32 + crow) * lda + ccol;
    const bf16* a1 = a0 + (size_t)16 * lda;
    const bf16* w0 = jb.W + (size_t)(bn + wave * 32 + crow) * ldw + ccol;
    const bf16* w1 = w0 + (size_t)16 * ldw;
    bf16* lA = As + wave * 1024;  // chunk 2w at +0, 2w+1 at +512
    bf16* lB = Bs + wave * 1024;
    f32x4 acc[4][4] = {};
    for (int k0 = 0; k0 < K; k0 += 32) {
        gld16(a0 + k0, lA);
        gld16(a1 + k0, lA + 512);
        gld16(w0 + k0, lB);
        gld16(w1 + k0, lB + 512);
        __syncthreads();  // compiler drains vmcnt before barrier
        bf16x8 af[4], bfr[4];
#pragma unroll
        for (int i = 0; i < 4; i++) {
            af[i]  = *(const bf16x8*)&As[(wm + i * 16 + m16) * 32 + quad * 8];
            bfr[i] = *(const bf16x8*)&Bs[(wn + i * 16 + m16) * 32 + quad * 8];
        }
#pragma unroll
        for (int i = 0; i < 4; i++)
#pragma unroll
            for (int j = 0; j < 4; j++)
                acc[i][j] = __builtin_amdgcn_mfma_f32_16x16x32_bf16(af[i], bfr[j], acc[i][j], 0, 0, 0);
        __syncthreads();
    }
#pragma unroll
    for (int j = 0; j < 4; j++) {
        const int col = bn + wn + j * 16 + m16;
        const float bv = jb.bias[col];
#pragma unroll
        for (int i = 0; i < 4; i++)
#pragma unroll
            for (int r = 0; r < 4; r++) {
                const int row = bm + wm + i * 16 + quad * 4 + r;
                float val = acc[i][j][r] + bv;
                if (jb.relu) val = fmaxf(val, 0.f);
                jb.C[(size_t)row * ldc + col] = (bf16)val;
            }
    }
}

// ---------------------------------------------------------------------------
// Old multi-job GEMM (reg-staged; fp32/dual-A paths). CA q proj + FFN1.
struct Job { const void* A; const void* A2; const float* W; const float* bias;
             bf16* C; int aty; int relu; };
struct Jobs5 { Job j[5]; };

__device__ inline void load_a(const Job& jb, size_t off, int k0, bf16x8& r) {
    if (jb.aty == 0)      r = ld8f((const float*)jb.A + off + k0);
    else if (jb.aty == 1) r = ld8b((const bf16*)jb.A + off + k0);
    else                  r = ld8bf((const bf16*)jb.A + off + k0,
                                    (const float*)jb.A2 + off + k0);
}

__global__ __launch_bounds__(256) void gemm_jobs(
    Jobs5 jobs, int lda, int ldw, int ldc, int K)
{
    __shared__ __align__(16) bf16 As[128][40];
    __shared__ __align__(16) bf16 Bs[128][40];
    int bx, by, bz;
    swz_xyz(bx, by, bz);
    const Job jb = jobs.j[bz];
    const int bm = by * 128, bn = bx * 128;
    const int tid = threadIdx.x;
    const int wave = tid >> 6, lane = tid & 63;
    const int wm = (wave >> 1) * 64, wn = (wave & 1) * 64;
    const int quad = lane >> 4, m16 = lane & 15;
    const int srow = tid >> 2, scol = (tid & 3) * 8;
    f32x4 acc[4][4] = {};
    const size_t aoff0 = (size_t)(bm + srow) * lda + scol;
    const size_t aoff1 = aoff0 + (size_t)64 * lda;
    const size_t woff0 = (size_t)(bn + srow) * ldw + scol;
    const size_t woff1 = woff0 + (size_t)64 * ldw;
    bf16x8 a0, a1, b0, b1;
    load_a(jb, aoff0, 0, a0);
    load_a(jb, aoff1, 0, a1);
    b0 = ld8f(jb.W + woff0);
    b1 = ld8f(jb.W + woff1);
    for (int k0 = 0; k0 < K; k0 += 32) {
        *(bf16x8*)&As[srow][scol]      = a0;
        *(bf16x8*)&As[srow + 64][scol] = a1;
        *(bf16x8*)&Bs[srow][scol]      = b0;
        *(bf16x8*)&Bs[srow + 64][scol] = b1;
        __syncthreads();
        const int kn = k0 + 32;
        if (kn < K) {
            load_a(jb, aoff0, kn, a0);
            load_a(jb, aoff1, kn, a1);
            b0 = ld8f(jb.W + woff0 + kn);
            b1 = ld8f(jb.W + woff1 + kn);
        }
        bf16x8 af[4], bfr[4];
#pragma unroll
        for (int i = 0; i < 4; i++) {
            af[i]  = *(const bf16x8*)&As[wm + i * 16 + m16][quad * 8];
            bfr[i] = *(const bf16x8*)&Bs[wn + i * 16 + m16][quad * 8];
        }
#pragma unroll
        for (int i = 0; i < 4; i++)
#pragma unroll
            for (int j = 0; j < 4; j++)
                acc[i][j] = __builtin_amdgcn_mfma_f32_16x16x32_bf16(af[i], bfr[j], acc[i][j], 0, 0, 0);
        __syncthreads();
    }
#pragma unroll
    for (int j = 0; j < 4; j++) {
        const int col = bn + wn + j * 16 + m16;
        const float bv = jb.bias[col];
#pragma unroll
        for (int i = 0; i < 4; i++)
#pragma unroll
            for (int r = 0; r < 4; r++) {
                const int row = bm + wm + i * 16 + quad * 4 + r;
                float val = acc[i][j][r] + bv;
                if (jb.relu) val = fmaxf(val, 0.f);
                jb.C[(size_t)row * ldc + col] = (bf16)val;
            }
    }
}

// ---------------------------------------------------------------------------
// Split-K GEMM: z = K-slice; fp32 partial out (no bias — folded into add_ln).
// ATY 1 = bf16 A; ATY 3 = fp32+fp32 dual A (PV partial pair). Pipelined.
template <int ATY>
__global__ __launch_bounds__(256) void gemm_sk(
    const void* __restrict__ A, const void* __restrict__ A2, int lda,
    const float* __restrict__ W, int ldw,
    float* __restrict__ Cp, size_t cstride, int ldc, int Ks)
{
    __shared__ __align__(16) bf16 As[128][40];
    __shared__ __align__(16) bf16 Bs[128][40];
    int bx, by, bz;
    swz_xyz(bx, by, bz);
    const int bm = by * 128, bn = bx * 128;
    const int kbase = bz * Ks;
    const int tid = threadIdx.x;
    const int wave = tid >> 6, lane = tid & 63;
    const int wm = (wave >> 1) * 64, wn = (wave & 1) * 64;
    const int quad = lane >> 4, m16 = lane & 15;
    const int srow = tid >> 2, scol = (tid & 3) * 8;
    f32x4 acc[4][4] = {};
    const size_t aoff0 = (size_t)(bm + srow) * lda + kbase + scol;
    const size_t aoff1 = aoff0 + (size_t)64 * lda;
    const size_t woff0 = (size_t)(bn + srow) * ldw + kbase + scol;
    const size_t woff1 = woff0 + (size_t)64 * ldw;
    bf16x8 a0, a1, b0, b1;
    if (ATY == 1) {
        a0 = ld8b((const bf16*)A + aoff0);
        a1 = ld8b((const bf16*)A + aoff1);
    } else {
        a0 = ld8ff((const float*)A + aoff0, (const float*)A2 + aoff0);
        a1 = ld8ff((const float*)A + aoff1, (const float*)A2 + aoff1);
    }
    b0 = ld8f(W + woff0);
    b1 = ld8f(W + woff1);
    for (int k0 = 0; k0 < Ks; k0 += 32) {
        *(bf16x8*)&As[srow][scol]      = a0;
        *(bf16x8*)&As[srow + 64][scol] = a1;
        *(bf16x8*)&Bs[srow][scol]      = b0;
        *(bf16x8*)&Bs[srow + 64][scol] = b1;
        __syncthreads();
        const int kn = k0 + 32;
        if (kn < Ks) {
            if (ATY == 1) {
                a0 = ld8b((const bf16*)A + aoff0 + kn);
                a1 = ld8b((const bf16*)A + aoff1 + kn);
            } else {
                a0 = ld8ff((const float*)A + aoff0 + kn, (const float*)A2 + aoff0 + kn);
                a1 = ld8ff((const float*)A + aoff1 + kn, (const float*)A2 + aoff1 + kn);
            }
            b0 = ld8f(W + woff0 + kn);
            b1 = ld8f(W + woff1 + kn);
        }
        bf16x8 af[4], bfr[4];
#pragma unroll
        for (int i = 0; i < 4; i++) {
            af[i]  = *(const bf16x8*)&As[wm + i * 16 + m16][quad * 8];
            bfr[i] = *(const bf16x8*)&Bs[wn + i * 16 + m16][quad * 8];
        }
#pragma unroll
        for (int i = 0; i < 4; i++)
#pragma unroll
            for (int j = 0; j < 4; j++)
                acc[i][j] = __builtin_amdgcn_mfma_f32_16x16x32_bf16(af[i], bfr[j], acc[i][j], 0, 0, 0);
        __syncthreads();
    }
    float* out = Cp + (size_t)bz * cstride;
#pragma unroll
    for (int j = 0; j < 4; j++) {
        const int col = bn + wn + j * 16 + m16;
#pragma unroll
        for (int i = 0; i < 4; i++)
#pragma unroll
            for (int r = 0; r < 4; r++) {
                const int row = bm + wm + i * 16 + quad * 4 + r;
                out[(size_t)row * ldc + col] = acc[i][j][r];
            }
    }
}

// ---------------------------------------------------------------------------
// scores[bh,l,s] = scale*(qc.kc + qp.kp), K=256. Grid (S/128, Lq/128, B*H).
// Both tiles via global_load_lds into linear [128][32] LDS.
__global__ __launch_bounds__(256) void attn_scores(
    const bf16* __restrict__ qc, const bf16* __restrict__ qp,
    const bf16* __restrict__ kc, const bf16* __restrict__ kp,
    bf16* __restrict__ scores, int Lq, int S, float scale)
{
    __shared__ __align__(16) bf16 As[128 * 32];
    __shared__ __align__(16) bf16 Bs[128 * 32];
    int bx, by, bz;
    swz_xyz(bx, by, bz);
    const int bh = bz;
    const int b = bh / NH, h = bh % NH;
    const int bm = by * 128, bn = bx * 128;
    const int tid = threadIdx.x;
    const int wave = tid >> 6, lane = tid & 63;
    const int wm = (wave >> 1) * 64, wn = (wave & 1) * 64;
    const int quad = lane >> 4, m16 = lane & 15;
    const int crow = lane >> 2, ccol = (lane & 3) * 8;
    const size_t hb = (size_t)b * D_MODEL + h * HD;
    const size_t ar0 = (size_t)(bm + wave * 32 + crow) * ROWSTRIDE + hb + ccol;
    const size_t ar1 = ar0 + (size_t)16 * ROWSTRIDE;
    const size_t br0 = (size_t)(bn + wave * 32 + crow) * ROWSTRIDE + hb + ccol;
    const size_t br1 = br0 + (size_t)16 * ROWSTRIDE;
    bf16* lA = As + wave * 1024;
    bf16* lB = Bs + wave * 1024;
    f32x4 acc[4][4] = {};
    for (int k0 = 0; k0 < 256; k0 += 32) {
        const bf16* qsrc = (k0 < 128) ? qc : qp;
        const bf16* ksrc = (k0 < 128) ? kc : kp;
        const int kcol = k0 & 127;
        gld16(qsrc + ar0 + kcol, lA);
        gld16(qsrc + ar1 + kcol, lA + 512);
        gld16(ksrc + br0 + kcol, lB);
        gld16(ksrc + br1 + kcol, lB + 512);
        __syncthreads();
        bf16x8 af[4], bfr[4];
#pragma unroll
        for (int i = 0; i < 4; i++) {
            af[i]  = *(const bf16x8*)&As[(wm + i * 16 + m16) * 32 + quad * 8];
            bfr[i] = *(const bf16x8*)&Bs[(wn + i * 16 + m16) * 32 + quad * 8];
        }
#pragma unroll
        for (int i = 0; i < 4; i++)
#pragma unroll
            for (int j = 0; j < 4; j++)
                acc[i][j] = __builtin_amdgcn_mfma_f32_16x16x32_bf16(af[i], bfr[j], acc[i][j], 0, 0, 0);
        __syncthreads();
    }
    bf16* sb = scores + (size_t)bh * Lq * S;
#pragma unroll
    for (int i = 0; i < 4; i++)
#pragma unroll
        for (int j = 0; j < 4; j++)
#pragma unroll
            for (int r = 0; r < 4; r++)
                sb[(size_t)(bm + wm + i * 16 + quad * 4 + r) * S + bn + wn + j * 16 + m16]
                    = (bf16)(acc[i][j][r] * scale);
}

// ---------------------------------------------------------------------------
// Fused softmax + head-mean. One block per (b,l): all NH=6 head rows.
template <int N>
__global__ __launch_bounds__(256) void softmax_mean(
    bf16* __restrict__ scores, float* __restrict__ att, int Lq)
{
    const int S = N << 8;
    const int l = blockIdx.x, b = blockIdx.y;
    const int tid = threadIdx.x;
    __shared__ float red[4], red2[4];
    float macc[N];
#pragma unroll
    for (int i = 0; i < N; i++) macc[i] = 0.f;
    for (int h = 0; h < NH; h++) {
        bf16* p = scores + ((size_t)(b * NH + h) * Lq + l) * S;
        float vals[N];
        float mx = -1e30f;
#pragma unroll
        for (int i = 0; i < N; i++) { vals[i] = (float)p[tid + (i << 8)]; mx = fmaxf(mx, vals[i]); }
        for (int off = 32; off; off >>= 1) mx = fmaxf(mx, __shfl_xor(mx, off, 64));
        if ((tid & 63) == 0) red[tid >> 6] = mx;
        __syncthreads();
        mx = fmaxf(fmaxf(red[0], red[1]), fmaxf(red[2], red[3]));
        float sum = 0.f;
#pragma unroll
        for (int i = 0; i < N; i++) { vals[i] = __expf(vals[i] - mx); sum += vals[i]; }
        for (int off = 32; off; off >>= 1) sum += __shfl_xor(sum, off, 64);
        if ((tid & 63) == 0) red2[tid >> 6] = sum;
        __syncthreads();
        const float inv = 1.f / (red2[0] + red2[1] + red2[2] + red2[3]);
#pragma unroll
        for (int i = 0; i < N; i++) {
            const float w = vals[i] * inv;
            p[tid + (i << 8)] = (bf16)w;
            macc[i] += w;
        }
    }
    float* ao = att + ((size_t)b * Lq + l) * S;
#pragma unroll
    for (int i = 0; i < N; i++) ao[tid + (i << 8)] = macc[i] * (1.f / 6.f);
}

// ---------------------------------------------------------------------------
// Split-S PV. A-side (softmax weights) via gload_lds; V transposed reg-scatter.
__global__ __launch_bounds__(256) void attn_pv_sk(
    const bf16* __restrict__ wsm, const bf16* __restrict__ v,
    float* __restrict__ Pv, size_t pstride, int Lq, int S)
{
    __shared__ __align__(16) bf16 As[128 * 32];
    __shared__ __align__(16) bf16 BsT[128][40];
    int bx, by, bz;
    swz_xyz(bx, by, bz);
    const int bh = bz;
    const int b = bh / NH, h = bh % NH;
    const int bm = bx * 128;
    const int kbase = by * (S >> 1);
    const int tid = threadIdx.x;
    const int wave = tid >> 6, lane = tid & 63;
    const int wm = (wave >> 1) * 64, wn = (wave & 1) * 64;
    const int quad = lane >> 4, m16 = lane & 15;
    const int crow = lane >> 2, ccol = (lane & 3) * 8;
    const int kk0 = tid >> 4, e0 = (tid & 15) * 8;
    f32x4 acc[4][4] = {};
    const bf16* wbase = wsm + (size_t)(bh * Lq + bm) * S + kbase;
    const size_t vb = (size_t)b * D_MODEL + h * HD;
    const bf16* a0 = wbase + (size_t)(wave * 32 + crow) * S + ccol;
    const bf16* a1 = a0 + (size_t)16 * S;
    bf16* lA = As + wave * 1024;
    bf16x8 v0, v1;
    v0 = *(const bf16x8*)(v + (size_t)(kbase + kk0) * ROWSTRIDE + vb + e0);
    v1 = *(const bf16x8*)(v + (size_t)(kbase + kk0 + 16) * ROWSTRIDE + vb + e0);
    for (int k0 = 0; k0 < (S >> 1); k0 += 32) {
        gld16(a0 + k0, lA);
        gld16(a1 + k0, lA + 512);
#pragma unroll
        for (int i = 0; i < 8; i++) { BsT[e0 + i][kk0] = v0[i]; BsT[e0 + i][kk0 + 16] = v1[i]; }
        __syncthreads();
        const int kn = k0 + 32;
        if (kn < (S >> 1)) {
            v0 = *(const bf16x8*)(v + (size_t)(kbase + kn + kk0) * ROWSTRIDE + vb + e0);
            v1 = *(const bf16x8*)(v + (size_t)(kbase + kn + kk0 + 16) * ROWSTRIDE + vb + e0);
        }
        bf16x8 af[4], bfr[4];
#pragma unroll
        for (int i = 0; i < 4; i++) {
            af[i]  = *(const bf16x8*)&As[(wm + i * 16 + m16) * 32 + quad * 8];
            bfr[i] = *(const bf16x8*)&BsT[wn + i * 16 + m16][quad * 8];
        }
#pragma unroll
        for (int i = 0; i < 4; i++)
#pragma unroll
            for (int j = 0; j < 4; j++)
                acc[i][j] = __builtin_amdgcn_mfma_f32_16x16x32_bf16(af[i], bfr[j], acc[i][j], 0, 0, 0);
        __syncthreads();
    }
    float* out = Pv + by * pstride;
#pragma unroll
    for (int i = 0; i < 4; i++)
#pragma unroll
        for (int j = 0; j < 4; j++)
#pragma unroll
            for (int r = 0; r < 4; r++)
                out[(size_t)(bm + wm + i * 16 + quad * 4 + r) * ROWSTRIDE + vb + wn + j * 16 + m16]
                    = acc[i][j][r];
}

// ---------------------------------------------------------------------------
// out = LN(resid + sum_{p<NP} P[p] + xbias) * g + be.
template <int NP, typename TR, typename TO>
__global__ __launch_bounds__(256) void add_ln_p(
    const TR* __restrict__ resid, const float* __restrict__ P, size_t pstride,
    const float* __restrict__ xbias,
    const float* __restrict__ g, const float* __restrict__ be, TO* __restrict__ out)
{
    const size_t base = (size_t)blockIdx.x * D_MODEL;
    const int tid = threadIdx.x;
    float v[3];
#pragma unroll
    for (int i = 0; i < 3; i++) {
        const int c = tid + (i << 8);
        float x = xbias[c];
#pragma unroll
        for (int p = 0; p < NP; p++) x += P[p * pstride + base + c];
        v[i] = (float)resid[base + c] + x;
    }
    float s = v[0] + v[1] + v[2];
    float s2 = v[0] * v[0] + v[1] * v[1] + v[2] * v[2];
    for (int off = 32; off; off >>= 1) { s += __shfl_xor(s, off, 64); s2 += __shfl_xor(s2, off, 64); }
    __shared__ float rs[4], rs2[4];
    if ((tid & 63) == 0) { rs[tid >> 6] = s; rs2[tid >> 6] = s2; }
    __syncthreads();
    s = rs[0] + rs[1] + rs[2] + rs[3];
    s2 = rs2[0] + rs2[1] + rs2[2] + rs2[3];
    const float mean = s * (1.f / 768.f);
    const float var = s2 * (1.f / 768.f) - mean * mean;
    const float inv = rsqrtf(var + 1e-5f);
#pragma unroll
    for (int i = 0; i < 3; i++) {
        const int c = tid + (i << 8);
        out[base + c] = (TO)((v[i] - mean) * inv * g[c] + be[c]);
    }
}

// ---------------------------------------------------------------------------
extern "C" void kernel_launch(void* const* d_in, const int* in_sizes, int n_in,
                              void* d_out, int out_size, void* d_ws, size_t ws_size,
                              hipStream_t stream)
{
    const float* tgt        = (const float*)d_in[0];
    const float* memory     = (const float*)d_in[1];
    const float* tgt_pos    = (const float*)d_in[2];
    const float* memory_pos = (const float*)d_in[3];
    const float* tgt_pos2   = (const float*)d_in[4];
    const float *sa_w[6], *sa_b[6], *ca_w[6], *ca_b[6];
    for (int i = 0; i < 6; i++) {
        sa_w[i] = (const float*)d_in[5 + 2 * i];  sa_b[i] = (const float*)d_in[6 + 2 * i];
        ca_w[i] = (const float*)d_in[17 + 2 * i]; ca_b[i] = (const float*)d_in[18 + 2 * i];
    }
    const float* ff1_w = (const float*)d_in[29]; const float* ff1_b = (const float*)d_in[30];
    const float* ff2_w = (const float*)d_in[31]; const float* ff2_b = (const float*)d_in[32];
    const float* ln_g[3] = {(const float*)d_in[33], (const float*)d_in[35], (const float*)d_in[37]};
    const float* ln_b[3] = {(const float*)d_in[34], (const float*)d_in[36], (const float*)d_in[38]};

    // ---- workspace (106,954,752 B) ----
    char* ws = (char*)d_ws;
    bf16* qc  = (bf16*)(ws);                // [0, 6291456)
    bf16* qp  = (bf16*)(ws + 6291456);      // [6291456, 12582912)
    bf16* kc  = (bf16*)(ws + 12582912);     // [12582912, 25165824)
    bf16* kp  = (bf16*)(ws + 25165824);     // [25165824, 37748736)
    bf16* vv  = (bf16*)(ws + 37748736);     // [37748736, 50331648)
    bf16* t1  = (bf16*)(ws + 50331648);     // [50331648, 56623104)
    bf16* sc  = (bf16*)(ws + 56623104);     // [56623104, 106954752) 50.33 MB
    const size_t PSTRIDE = 3145728;  // floats per 12.58 MB slice
    float* pv_sa = (float*)(ws + 81788928);  // sc_hi: SA PV pair (sc_lo = SA scores live)
    float* pv_ca = (float*)(ws + 12582912);  // kc+kp: dead after CA scores
    float* op    = (float*)(ws + 56623104);  // sc_lo: out-proj pair (both phases)
    float* fp    = (float*)(ws + 56623104);  // FFN2 4-slice = full sc (dead)
    bf16*  tca   = kc;                       // Pv_ca dead after CA out-proj
    bf16*  ffh   = kp;                       // 16.78 MB over dead kp+vv

    // bf16 staging copies (liveness-checked):
    //  - tgt_b/tgtpos_b in sc[0..12.6 MB): live only during SA proj (SA scores
    //    overwrite sc after).
    //  - mem_b/mempos_b in sc[0..25.2 MB): written after add_ln1 (op dead),
    //    live during CA kv; CA scores overwrite after.
    //  - 8 hot weight mats (sa 0..4, ca 2..4) bf16 in d_out's out_t region
    //    (9.4 MB of 12.58; out_t written only by the final add_ln).
    bf16* tgt_b    = sc;
    bf16* tgtpos_b = sc + 3145728;
    bf16* mem_b    = sc;
    bf16* mempos_b = sc + 6291456;
    bf16* wb       = (bf16*)d_out;
    const size_t WSTEP = 589824;  // 768*768

    float* out_t    = (float*)d_out;        // (L,B,D)
    float* out_att  = out_t + 3145728;      // (B,L,S)
    float* out_satt = out_att + 4194304;    // (B,L,L)

    const dim3 blk(256);
    const float SCALE = 0.0625f;

    // ---- cvt pass 1: 8 weights + tgt + tgt_pos ----
    {
        CvtJobs C = {};
        for (int i = 0; i < 5; i++) C.j[i] = {sa_w[i], wb + i * WSTEP, 73728};
        for (int i = 0; i < 3; i++) C.j[5 + i] = {ca_w[2 + i], wb + (5 + i) * WSTEP, 73728};
        C.j[8] = {tgt,     tgt_b,    393216};
        C.j[9] = {tgt_pos, tgtpos_b, 393216};
        cvt_multi<<<dim3(288, 10), blk, 0, stream>>>(C);
    }

    // ---- self attention ----
    {
        JobsB J = {};
        J.j[0] = {tgtpos_b, wb + 0 * WSTEP, sa_b[0], qc, 0};
        J.j[1] = {tgt_b,    wb + 1 * WSTEP, sa_b[1], qp, 0};
        J.j[2] = {tgtpos_b, wb + 2 * WSTEP, sa_b[2], kc, 0};
        J.j[3] = {tgt_b,    wb + 3 * WSTEP, sa_b[3], kp, 0};
        J.j[4] = {tgt_b,    wb + 4 * WSTEP, sa_b[4], vv, 0};
        gemm_bb<<<dim3(6, 32, 5), blk, 0, stream>>>(J, 768, 768, 768, 768);
    }
    attn_scores<<<dim3(4, 4, 48), blk, 0, stream>>>(qc, qp, kc, kp, sc, 512, 512, SCALE);
    softmax_mean<2><<<dim3(512, 8), blk, 0, stream>>>(sc, out_satt, 512);
    attn_pv_sk<<<dim3(4, 2, 48), blk, 0, stream>>>(sc, vv, pv_sa, PSTRIDE, 512, 512);
    gemm_sk<3><<<dim3(6, 32, 2), blk, 0, stream>>>(pv_sa, pv_sa + PSTRIDE, 768,
                                                   sa_w[5], 768, op, PSTRIDE, 768, 384);
    add_ln_p<2, float, bf16><<<dim3(4096), blk, 0, stream>>>(tgt, op, PSTRIDE, sa_b[5],
                                                             ln_g[0], ln_b[0], t1);

    // ---- cvt pass 2: memory + memory_pos (sc_lo dead now) ----
    {
        CvtJobs C = {};
        C.j[0] = {memory,     mem_b,    786432};
        C.j[1] = {memory_pos, mempos_b, 786432};
        cvt_multi<<<dim3(288, 2), blk, 0, stream>>>(C);
    }

    // ---- cross attention ----
    {
        Jobs5 J = {};
        J.j[0] = {tgt_pos, nullptr,  ca_w[0], ca_b[0], qc, 0, 0};
        J.j[1] = {t1,      tgt_pos2, ca_w[1], ca_b[1], qp, 2, 0};
        gemm_jobs<<<dim3(6, 32, 2), blk, 0, stream>>>(J, 768, 768, 768, 768);
    }
    {
        JobsB J = {};
        J.j[0] = {mem_b,    wb + 5 * WSTEP, ca_b[2], kc, 0};
        J.j[1] = {mempos_b, wb + 6 * WSTEP, ca_b[3], kp, 0};
        J.j[2] = {mempos_b, wb + 7 * WSTEP, ca_b[4], vv, 0};
        gemm_bb<<<dim3(6, 64, 3), blk, 0, stream>>>(J, 768, 768, 768, 768);
    }
    attn_scores<<<dim3(8, 4, 48), blk, 0, stream>>>(qc, qp, kc, kp, sc, 512, 1024, SCALE);
    softmax_mean<4><<<dim3(512, 8), blk, 0, stream>>>(sc, out_att, 512);
    attn_pv_sk<<<dim3(4, 2, 48), blk, 0, stream>>>(sc, vv, pv_ca, PSTRIDE, 512, 1024);
    gemm_sk<3><<<dim3(6, 32, 2), blk, 0, stream>>>(pv_ca, pv_ca + PSTRIDE, 768,
                                                   ca_w[5], 768, op, PSTRIDE, 768, 384);
    add_ln_p<2, bf16, bf16><<<dim3(4096), blk, 0, stream>>>(t1, op, PSTRIDE, ca_b[5],
                                                            ln_g[1], ln_b[1], tca);

    // ---- FFN ----
    {
        Jobs5 J = {};
        J.j[0] = {tca, nullptr, ff1_w, ff1_b, ffh, 1, 1};
        gemm_jobs<<<dim3(16, 32, 1), blk, 0, stream>>>(J, 768, 768, 2048, 768);
    }
    gemm_sk<1><<<dim3(6, 32, 4), blk, 0, stream>>>(ffh, nullptr, 2048,
                                                   ff2_w, 2048, fp, PSTRIDE, 768, 512);
    add_ln_p<4, bf16, float><<<dim3(4096), blk, 0, stream>>>(tca, fp, PSTRIDE, ff2_b,
                                                             ln_g[2], ln_b[2], out_t);
}

// Round 7
// 624.313 us; speedup vs baseline: 1.2505x; 1.0518x over previous
//
#include <hip/hip_runtime.h>

// Conditional-DETR decoder layer, MI355X gfx950.
// R13 green @ 656.6 us. gemm_bb (gload_lds) removed SA proj/CA kv from top-5.
// New #1: CA q proj on OLD reg-staged path: 62 us, Occ 13% (1.5 blk/CU),
// Mfma 5.4%, VALU 6.3%, HBM 7.6% -> pure latency, fp32 staging chain exposed.
// R14 (this): finish migration; all GEMMs except out-projs go bf16+gload_lds:
//  - cvt1 += ca_w[0..1] (10 W total in out_t region) + tgt_pos->tp_b in
//    out_att region (persists to CA q; also serves SA proj).
//  - cvt2 += qpin_b = bf16((float)t1 + tgt_pos2)  [== old in-GEMM ld8bf].
//  - CA q -> gemm_bb; cvt3 (after CA scores): ff1_w/ff2_w -> bf16 in dead
//    qc/qp; FFN1 -> gemm_bb; FFN2 -> gemm_sk_bb (split-K fp32 partials).
// Bit-identical rounding everywhere: absmax must stay 0.03125.
// Predict: CA q 62->~30, FFN1 ->~35, FFN2 ->~35; total 656 -> ~590-610.

typedef __bf16 bf16;
typedef __attribute__((ext_vector_type(8))) __bf16 bf16x8;
typedef __attribute__((ext_vector_type(4))) float f32x4;

#define D_MODEL 768
#define NH 6
#define HD 128
#define ROWSTRIDE (8 * D_MODEL)  // 6144 (B*D)

// XCD-aware chunked swizzle: requires gridDim.x*y*z % 8 == 0 (all our grids).
__device__ inline void swz_xyz(int& x, int& y, int& z) {
    const int nx = gridDim.x, ny = gridDim.y;
    const int n = nx * ny * gridDim.z;
    const int flat = blockIdx.x + nx * (blockIdx.y + ny * blockIdx.z);
    const int t = (flat & 7) * (n >> 3) + (flat >> 3);
    x = t % nx;
    const int r = t / nx;
    y = r % ny;
    z = r / ny;
}

// global->LDS direct DMA, 16 B per lane. Dest is wave-uniform base + lane*16.
__device__ __forceinline__ void gld16(const bf16* g, bf16* l) {
    __builtin_amdgcn_global_load_lds(
        (const __attribute__((address_space(1))) unsigned int*)g,
        (__attribute__((address_space(3))) unsigned int*)l, 16, 0, 0);
}

// 8-elem staging loaders -> bf16x8
__device__ inline bf16x8 ld8f(const float* p) {
    f32x4 a = *(const f32x4*)p, b = *(const f32x4*)(p + 4);
    bf16x8 r;
#pragma unroll
    for (int i = 0; i < 4; i++) { r[i] = (bf16)a[i]; r[i + 4] = (bf16)b[i]; }
    return r;
}
__device__ inline bf16x8 ld8bf(const bf16* p, const float* q) {  // bf16 + f32
    bf16x8 x = *(const bf16x8*)p;
    f32x4 a = *(const f32x4*)q, b = *(const f32x4*)(q + 4);
    bf16x8 r;
#pragma unroll
    for (int i = 0; i < 4; i++) { r[i] = (bf16)((float)x[i] + a[i]); r[i + 4] = (bf16)((float)x[i + 4] + b[i]); }
    return r;
}
__device__ inline bf16x8 ld8ff(const float* p, const float* q) {  // f32 + f32
    f32x4 a = *(const f32x4*)p, b = *(const f32x4*)(p + 4);
    f32x4 c = *(const f32x4*)q, d = *(const f32x4*)(q + 4);
    bf16x8 r;
#pragma unroll
    for (int i = 0; i < 4; i++) { r[i] = (bf16)(a[i] + c[i]); r[i + 4] = (bf16)(b[i] + d[i]); }
    return r;
}

// ---------------------------------------------------------------------------
// Multi-segment conversion (grid-stride; blockIdx.y = job).
// add == nullptr: dst = bf16(src). else: dst = bf16((float)add + src).
struct CvtJob { const float* src; const bf16* add; bf16* dst; int nvec; };
struct CvtJobs { CvtJob j[12]; };

__global__ __launch_bounds__(256) void cvt_multi(CvtJobs jobs)
{
    const CvtJob jb = jobs.j[blockIdx.y];
    const int stride = gridDim.x * 256;
    if (jb.add) {
        for (int i = blockIdx.x * 256 + threadIdx.x; i < jb.nvec; i += stride)
            *(bf16x8*)(jb.dst + (size_t)i * 8) = ld8bf(jb.add + (size_t)i * 8, jb.src + (size_t)i * 8);
    } else {
        for (int i = blockIdx.x * 256 + threadIdx.x; i < jb.nvec; i += stride)
            *(bf16x8*)(jb.dst + (size_t)i * 8) = ld8f(jb.src + (size_t)i * 8);
    }
}

// ---------------------------------------------------------------------------
// All-bf16 multi-job GEMM with global_load_lds staging (m97 structure).
// C[M,N] = A[M,K] * W[N,K]^T + bias. Linear LDS [128][32] per operand.
struct JobB { const bf16* A; const bf16* W; const float* bias; bf16* C; int relu; };
struct JobsB { JobB j[5]; };

__global__ __launch_bounds__(256) void gemm_bb(
    JobsB jobs, int lda, int ldw, int ldc, int K)
{
    __shared__ __align__(16) bf16 As[128 * 32];
    __shared__ __align__(16) bf16 Bs[128 * 32];
    int bx, by, bz;
    swz_xyz(bx, by, bz);
    const JobB jb = jobs.j[bz];
    const int bm = by * 128, bn = bx * 128;
    const int tid = threadIdx.x;
    const int wave = tid >> 6, lane = tid & 63;
    const int wm = (wave >> 1) * 64, wn = (wave & 1) * 64;
    const int quad = lane >> 4, m16 = lane & 15;
    const int crow = lane >> 2, ccol = (lane & 3) * 8;
    const bf16* a0 = jb.A + (size_t)(bm + wave * 32 + crow) * lda + ccol;
    const bf16* a1 = a0 + (size_t)16 * lda;
    const bf16* w0 = jb.W + (size_t)(bn + wave * 32 + crow) * ldw + ccol;
    const bf16* w1 = w0 + (size_t)16 * ldw;
    bf16* lA = As + wave * 1024;
    bf16* lB = Bs + wave * 1024;
    f32x4 acc[4][4] = {};
    for (int k0 = 0; k0 < K; k0 += 32) {
        gld16(a0 + k0, lA);
        gld16(a1 + k0, lA + 512);
        gld16(w0 + k0, lB);
        gld16(w1 + k0, lB + 512);
        __syncthreads();
        bf16x8 af[4], bfr[4];
#pragma unroll
        for (int i = 0; i < 4; i++) {
            af[i]  = *(const bf16x8*)&As[(wm + i * 16 + m16) * 32 + quad * 8];
            bfr[i] = *(const bf16x8*)&Bs[(wn + i * 16 + m16) * 32 + quad * 8];
        }
#pragma unroll
        for (int i = 0; i < 4; i++)
#pragma unroll
            for (int j = 0; j < 4; j++)
                acc[i][j] = __builtin_amdgcn_mfma_f32_16x16x32_bf16(af[i], bfr[j], acc[i][j], 0, 0, 0);
        __syncthreads();
    }
#pragma unroll
    for (int j = 0; j < 4; j++) {
        const int col = bn + wn + j * 16 + m16;
        const float bv = jb.bias[col];
#pragma unroll
        for (int i = 0; i < 4; i++)
#pragma unroll
            for (int r = 0; r < 4; r++) {
                const int row = bm + wm + i * 16 + quad * 4 + r;
                float val = acc[i][j][r] + bv;
                if (jb.relu) val = fmaxf(val, 0.f);
                jb.C[(size_t)row * ldc + col] = (bf16)val;
            }
    }
}

// ---------------------------------------------------------------------------
// All-bf16 split-K GEMM, gload_lds staging, fp32 partials (FFN2).
__global__ __launch_bounds__(256) void gemm_sk_bb(
    const bf16* __restrict__ A, int lda, const bf16* __restrict__ W, int ldw,
    float* __restrict__ Cp, size_t cstride, int ldc, int Ks)
{
    __shared__ __align__(16) bf16 As[128 * 32];
    __shared__ __align__(16) bf16 Bs[128 * 32];
    int bx, by, bz;
    swz_xyz(bx, by, bz);
    const int bm = by * 128, bn = bx * 128;
    const int kbase = bz * Ks;
    const int tid = threadIdx.x;
    const int wave = tid >> 6, lane = tid & 63;
    const int wm = (wave >> 1) * 64, wn = (wave & 1) * 64;
    const int quad = lane >> 4, m16 = lane & 15;
    const int crow = lane >> 2, ccol = (lane & 3) * 8;
    const bf16* a0 = A + (size_t)(bm + wave * 32 + crow) * lda + kbase + ccol;
    const bf16* a1 = a0 + (size_t)16 * lda;
    const bf16* w0 = W + (size_t)(bn + wave * 32 + crow) * ldw + kbase + ccol;
    const bf16* w1 = w0 + (size_t)16 * ldw;
    bf16* lA = As + wave * 1024;
    bf16* lB = Bs + wave * 1024;
    f32x4 acc[4][4] = {};
    for (int k0 = 0; k0 < Ks; k0 += 32) {
        gld16(a0 + k0, lA);
        gld16(a1 + k0, lA + 512);
        gld16(w0 + k0, lB);
        gld16(w1 + k0, lB + 512);
        __syncthreads();
        bf16x8 af[4], bfr[4];
#pragma unroll
        for (int i = 0; i < 4; i++) {
            af[i]  = *(const bf16x8*)&As[(wm + i * 16 + m16) * 32 + quad * 8];
            bfr[i] = *(const bf16x8*)&Bs[(wn + i * 16 + m16) * 32 + quad * 8];
        }
#pragma unroll
        for (int i = 0; i < 4; i++)
#pragma unroll
            for (int j = 0; j < 4; j++)
                acc[i][j] = __builtin_amdgcn_mfma_f32_16x16x32_bf16(af[i], bfr[j], acc[i][j], 0, 0, 0);
        __syncthreads();
    }
    float* out = Cp + (size_t)bz * cstride;
#pragma unroll
    for (int j = 0; j < 4; j++) {
        const int col = bn + wn + j * 16 + m16;
#pragma unroll
        for (int i = 0; i < 4; i++)
#pragma unroll
            for (int r = 0; r < 4; r++) {
                const int row = bm + wm + i * 16 + quad * 4 + r;
                out[(size_t)row * ldc + col] = acc[i][j][r];
            }
    }
}

// ---------------------------------------------------------------------------
// Split-K GEMM, reg-staged: dual-fp32 A (PV partial pair) x fp32 W. Out-projs.
__global__ __launch_bounds__(256) void gemm_sk3(
    const float* __restrict__ A, const float* __restrict__ A2, int lda,
    const float* __restrict__ W, int ldw,
    float* __restrict__ Cp, size_t cstride, int ldc, int Ks)
{
    __shared__ __align__(16) bf16 As[128][40];
    __shared__ __align__(16) bf16 Bs[128][40];
    int bx, by, bz;
    swz_xyz(bx, by, bz);
    const int bm = by * 128, bn = bx * 128;
    const int kbase = bz * Ks;
    const int tid = threadIdx.x;
    const int wave = tid >> 6, lane = tid & 63;
    const int wm = (wave >> 1) * 64, wn = (wave & 1) * 64;
    const int quad = lane >> 4, m16 = lane & 15;
    const int srow = tid >> 2, scol = (tid & 3) * 8;
    f32x4 acc[4][4] = {};
    const size_t aoff0 = (size_t)(bm + srow) * lda + kbase + scol;
    const size_t aoff1 = aoff0 + (size_t)64 * lda;
    const size_t woff0 = (size_t)(bn + srow) * ldw + kbase + scol;
    const size_t woff1 = woff0 + (size_t)64 * ldw;
    bf16x8 a0, a1, b0, b1;
    a0 = ld8ff(A + aoff0, A2 + aoff0);
    a1 = ld8ff(A + aoff1, A2 + aoff1);
    b0 = ld8f(W + woff0);
    b1 = ld8f(W + woff1);
    for (int k0 = 0; k0 < Ks; k0 += 32) {
        *(bf16x8*)&As[srow][scol]      = a0;
        *(bf16x8*)&As[srow + 64][scol] = a1;
        *(bf16x8*)&Bs[srow][scol]      = b0;
        *(bf16x8*)&Bs[srow + 64][scol] = b1;
        __syncthreads();
        const int kn = k0 + 32;
        if (kn < Ks) {
            a0 = ld8ff(A + aoff0 + kn, A2 + aoff0 + kn);
            a1 = ld8ff(A + aoff1 + kn, A2 + aoff1 + kn);
            b0 = ld8f(W + woff0 + kn);
            b1 = ld8f(W + woff1 + kn);
        }
        bf16x8 af[4], bfr[4];
#pragma unroll
        for (int i = 0; i < 4; i++) {
            af[i]  = *(const bf16x8*)&As[wm + i * 16 + m16][quad * 8];
            bfr[i] = *(const bf16x8*)&Bs[wn + i * 16 + m16][quad * 8];
        }
#pragma unroll
        for (int i = 0; i < 4; i++)
#pragma unroll
            for (int j = 0; j < 4; j++)
                acc[i][j] = __builtin_amdgcn_mfma_f32_16x16x32_bf16(af[i], bfr[j], acc[i][j], 0, 0, 0);
        __syncthreads();
    }
    float* out = Cp + (size_t)bz * cstride;
#pragma unroll
    for (int j = 0; j < 4; j++) {
        const int col = bn + wn + j * 16 + m16;
#pragma unroll
        for (int i = 0; i < 4; i++)
#pragma unroll
            for (int r = 0; r < 4; r++) {
                const int row = bm + wm + i * 16 + quad * 4 + r;
                out[(size_t)row * ldc + col] = acc[i][j][r];
            }
    }
}

// ---------------------------------------------------------------------------
// scores[bh,l,s] = scale*(qc.kc + qp.kp), K=256. Both tiles via gload_lds.
__global__ __launch_bounds__(256) void attn_scores(
    const bf16* __restrict__ qc, const bf16* __restrict__ qp,
    const bf16* __restrict__ kc, const bf16* __restrict__ kp,
    bf16* __restrict__ scores, int Lq, int S, float scale)
{
    __shared__ __align__(16) bf16 As[128 * 32];
    __shared__ __align__(16) bf16 Bs[128 * 32];
    int bx, by, bz;
    swz_xyz(bx, by, bz);
    const int bh = bz;
    const int b = bh / NH, h = bh % NH;
    const int bm = by * 128, bn = bx * 128;
    const int tid = threadIdx.x;
    const int wave = tid >> 6, lane = tid & 63;
    const int wm = (wave >> 1) * 64, wn = (wave & 1) * 64;
    const int quad = lane >> 4, m16 = lane & 15;
    const int crow = lane >> 2, ccol = (lane & 3) * 8;
    const size_t hb = (size_t)b * D_MODEL + h * HD;
    const size_t ar0 = (size_t)(bm + wave * 32 + crow) * ROWSTRIDE + hb + ccol;
    const size_t ar1 = ar0 + (size_t)16 * ROWSTRIDE;
    const size_t br0 = (size_t)(bn + wave * 32 + crow) * ROWSTRIDE + hb + ccol;
    const size_t br1 = br0 + (size_t)16 * ROWSTRIDE;
    bf16* lA = As + wave * 1024;
    bf16* lB = Bs + wave * 1024;
    f32x4 acc[4][4] = {};
    for (int k0 = 0; k0 < 256; k0 += 32) {
        const bf16* qsrc = (k0 < 128) ? qc : qp;
        const bf16* ksrc = (k0 < 128) ? kc : kp;
        const int kcol = k0 & 127;
        gld16(qsrc + ar0 + kcol, lA);
        gld16(qsrc + ar1 + kcol, lA + 512);
        gld16(ksrc + br0 + kcol, lB);
        gld16(ksrc + br1 + kcol, lB + 512);
        __syncthreads();
        bf16x8 af[4], bfr[4];
#pragma unroll
        for (int i = 0; i < 4; i++) {
            af[i]  = *(const bf16x8*)&As[(wm + i * 16 + m16) * 32 + quad * 8];
            bfr[i] = *(const bf16x8*)&Bs[(wn + i * 16 + m16) * 32 + quad * 8];
        }
#pragma unroll
        for (int i = 0; i < 4; i++)
#pragma unroll
            for (int j = 0; j < 4; j++)
                acc[i][j] = __builtin_amdgcn_mfma_f32_16x16x32_bf16(af[i], bfr[j], acc[i][j], 0, 0, 0);
        __syncthreads();
    }
    bf16* sb = scores + (size_t)bh * Lq * S;
#pragma unroll
    for (int i = 0; i < 4; i++)
#pragma unroll
        for (int j = 0; j < 4; j++)
#pragma unroll
            for (int r = 0; r < 4; r++)
                sb[(size_t)(bm + wm + i * 16 + quad * 4 + r) * S + bn + wn + j * 16 + m16]
                    = (bf16)(acc[i][j][r] * scale);
}

// ---------------------------------------------------------------------------
// Fused softmax + head-mean. One block per (b,l): all NH=6 head rows.
template <int N>
__global__ __launch_bounds__(256) void softmax_mean(
    bf16* __restrict__ scores, float* __restrict__ att, int Lq)
{
    const int S = N << 8;
    const int l = blockIdx.x, b = blockIdx.y;
    const int tid = threadIdx.x;
    __shared__ float red[4], red2[4];
    float macc[N];
#pragma unroll
    for (int i = 0; i < N; i++) macc[i] = 0.f;
    for (int h = 0; h < NH; h++) {
        bf16* p = scores + ((size_t)(b * NH + h) * Lq + l) * S;
        float vals[N];
        float mx = -1e30f;
#pragma unroll
        for (int i = 0; i < N; i++) { vals[i] = (float)p[tid + (i << 8)]; mx = fmaxf(mx, vals[i]); }
        for (int off = 32; off; off >>= 1) mx = fmaxf(mx, __shfl_xor(mx, off, 64));
        if ((tid & 63) == 0) red[tid >> 6] = mx;
        __syncthreads();
        mx = fmaxf(fmaxf(red[0], red[1]), fmaxf(red[2], red[3]));
        float sum = 0.f;
#pragma unroll
        for (int i = 0; i < N; i++) { vals[i] = __expf(vals[i] - mx); sum += vals[i]; }
        for (int off = 32; off; off >>= 1) sum += __shfl_xor(sum, off, 64);
        if ((tid & 63) == 0) red2[tid >> 6] = sum;
        __syncthreads();
        const float inv = 1.f / (red2[0] + red2[1] + red2[2] + red2[3]);
#pragma unroll
        for (int i = 0; i < N; i++) {
            const float w = vals[i] * inv;
            p[tid + (i << 8)] = (bf16)w;
            macc[i] += w;
        }
    }
    float* ao = att + ((size_t)b * Lq + l) * S;
#pragma unroll
    for (int i = 0; i < N; i++) ao[tid + (i << 8)] = macc[i] * (1.f / 6.f);
}

// ---------------------------------------------------------------------------
// Split-S PV. A-side (softmax weights) via gload_lds; V transposed reg-scatter.
__global__ __launch_bounds__(256) void attn_pv_sk(
    const bf16* __restrict__ wsm, const bf16* __restrict__ v,
    float* __restrict__ Pv, size_t pstride, int Lq, int S)
{
    __shared__ __align__(16) bf16 As[128 * 32];
    __shared__ __align__(16) bf16 BsT[128][40];
    int bx, by, bz;
    swz_xyz(bx, by, bz);
    const int bh = bz;
    const int b = bh / NH, h = bh % NH;
    const int bm = bx * 128;
    const int kbase = by * (S >> 1);
    const int tid = threadIdx.x;
    const int wave = tid >> 6, lane = tid & 63;
    const int wm = (wave >> 1) * 64, wn = (wave & 1) * 64;
    const int quad = lane >> 4, m16 = lane & 15;
    const int crow = lane >> 2, ccol = (lane & 3) * 8;
    const int kk0 = tid >> 4, e0 = (tid & 15) * 8;
    f32x4 acc[4][4] = {};
    const bf16* wbase = wsm + (size_t)(bh * Lq + bm) * S + kbase;
    const size_t vb = (size_t)b * D_MODEL + h * HD;
    const bf16* a0 = wbase + (size_t)(wave * 32 + crow) * S + ccol;
    const bf16* a1 = a0 + (size_t)16 * S;
    bf16* lA = As + wave * 1024;
    bf16x8 v0, v1;
    v0 = *(const bf16x8*)(v + (size_t)(kbase + kk0) * ROWSTRIDE + vb + e0);
    v1 = *(const bf16x8*)(v + (size_t)(kbase + kk0 + 16) * ROWSTRIDE + vb + e0);
    for (int k0 = 0; k0 < (S >> 1); k0 += 32) {
        gld16(a0 + k0, lA);
        gld16(a1 + k0, lA + 512);
#pragma unroll
        for (int i = 0; i < 8; i++) { BsT[e0 + i][kk0] = v0[i]; BsT[e0 + i][kk0 + 16] = v1[i]; }
        __syncthreads();
        const int kn = k0 + 32;
        if (kn < (S >> 1)) {
            v0 = *(const bf16x8*)(v + (size_t)(kbase + kn + kk0) * ROWSTRIDE + vb + e0);
            v1 = *(const bf16x8*)(v + (size_t)(kbase + kn + kk0 + 16) * ROWSTRIDE + vb + e0);
        }
        bf16x8 af[4], bfr[4];
#pragma unroll
        for (int i = 0; i < 4; i++) {
            af[i]  = *(const bf16x8*)&As[(wm + i * 16 + m16) * 32 + quad * 8];
            bfr[i] = *(const bf16x8*)&BsT[wn + i * 16 + m16][quad * 8];
        }
#pragma unroll
        for (int i = 0; i < 4; i++)
#pragma unroll
            for (int j = 0; j < 4; j++)
                acc[i][j] = __builtin_amdgcn_mfma_f32_16x16x32_bf16(af[i], bfr[j], acc[i][j], 0, 0, 0);
        __syncthreads();
    }
    float* out = Pv + by * pstride;
#pragma unroll
    for (int i = 0; i < 4; i++)
#pragma unroll
        for (int j = 0; j < 4; j++)
#pragma unroll
            for (int r = 0; r < 4; r++)
                out[(size_t)(bm + wm + i * 16 + quad * 4 + r) * ROWSTRIDE + vb + wn + j * 16 + m16]
                    = acc[i][j][r];
}

// ---------------------------------------------------------------------------
// out = LN(resid + sum_{p<NP} P[p] + xbias) * g + be.
template <int NP, typename TR, typename TO>
__global__ __launch_bounds__(256) void add_ln_p(
    const TR* __restrict__ resid, const float* __restrict__ P, size_t pstride,
    const float* __restrict__ xbias,
    const float* __restrict__ g, const float* __restrict__ be, TO* __restrict__ out)
{
    const size_t base = (size_t)blockIdx.x * D_MODEL;
    const int tid = threadIdx.x;
    float v[3];
#pragma unroll
    for (int i = 0; i < 3; i++) {
        const int c = tid + (i << 8);
        float x = xbias[c];
#pragma unroll
        for (int p = 0; p < NP; p++) x += P[p * pstride + base + c];
        v[i] = (float)resid[base + c] + x;
    }
    float s = v[0] + v[1] + v[2];
    float s2 = v[0] * v[0] + v[1] * v[1] + v[2] * v[2];
    for (int off = 32; off; off >>= 1) { s += __shfl_xor(s, off, 64); s2 += __shfl_xor(s2, off, 64); }
    __shared__ float rs[4], rs2[4];
    if ((tid & 63) == 0) { rs[tid >> 6] = s; rs2[tid >> 6] = s2; }
    __syncthreads();
    s = rs[0] + rs[1] + rs[2] + rs[3];
    s2 = rs2[0] + rs2[1] + rs2[2] + rs2[3];
    const float mean = s * (1.f / 768.f);
    const float var = s2 * (1.f / 768.f) - mean * mean;
    const float inv = rsqrtf(var + 1e-5f);
#pragma unroll
    for (int i = 0; i < 3; i++) {
        const int c = tid + (i << 8);
        out[base + c] = (TO)((v[i] - mean) * inv * g[c] + be[c]);
    }
}

// ---------------------------------------------------------------------------
extern "C" void kernel_launch(void* const* d_in, const int* in_sizes, int n_in,
                              void* d_out, int out_size, void* d_ws, size_t ws_size,
                              hipStream_t stream)
{
    const float* tgt        = (const float*)d_in[0];
    const float* memory     = (const float*)d_in[1];
    const float* tgt_pos    = (const float*)d_in[2];
    const float* memory_pos = (const float*)d_in[3];
    const float* tgt_pos2   = (const float*)d_in[4];
    const float *sa_w[6], *sa_b[6], *ca_w[6], *ca_b[6];
    for (int i = 0; i < 6; i++) {
        sa_w[i] = (const float*)d_in[5 + 2 * i];  sa_b[i] = (const float*)d_in[6 + 2 * i];
        ca_w[i] = (const float*)d_in[17 + 2 * i]; ca_b[i] = (const float*)d_in[18 + 2 * i];
    }
    const float* ff1_w = (const float*)d_in[29]; const float* ff1_b = (const float*)d_in[30];
    const float* ff2_w = (const float*)d_in[31]; const float* ff2_b = (const float*)d_in[32];
    const float* ln_g[3] = {(const float*)d_in[33], (const float*)d_in[35], (const float*)d_in[37]};
    const float* ln_b[3] = {(const float*)d_in[34], (const float*)d_in[36], (const float*)d_in[38]};

    // ---- workspace (106,954,752 B) ----
    char* ws = (char*)d_ws;
    bf16* qc  = (bf16*)(ws);                // [0, 6291456)
    bf16* qp  = (bf16*)(ws + 6291456);      // [6291456, 12582912)
    bf16* kc  = (bf16*)(ws + 12582912);     // [12582912, 25165824)
    bf16* kp  = (bf16*)(ws + 25165824);     // [25165824, 37748736)
    bf16* vv  = (bf16*)(ws + 37748736);     // [37748736, 50331648)
    bf16* t1  = (bf16*)(ws + 50331648);     // [50331648, 56623104)
    bf16* sc  = (bf16*)(ws + 56623104);     // [56623104, 106954752) 50.33 MB
    const size_t PSTRIDE = 3145728;  // floats per 12.58 MB slice
    float* pv_sa = (float*)(ws + 81788928);  // sc_hi: SA PV pair (sc_lo = SA scores live)
    float* pv_ca = (float*)(ws + 12582912);  // kc+kp: dead after CA scores
    float* op    = (float*)(ws + 56623104);  // sc_lo: out-proj pair (both phases)
    float* fp    = (float*)(ws + 56623104);  // FFN2 4-slice = full sc (dead)
    bf16*  tca   = kc;                       // Pv_ca dead after CA out-proj
    bf16*  ffh   = kp;                       // 16.78 MB over dead kp+vv

    // bf16 staging (liveness-checked):
    //  - tgt_b in sc[0..6.3 MB): live only during SA proj.
    //  - tp_b (tgt_pos bf16) + qpin_b (bf16(t1+tgt_pos2)) in d_out's out_att
    //    region [12.58, 29.36 MB): free until CA softmax_mean writes out_att.
    //  - 10 weight mats bf16 in out_t region (11.8 of 12.58 MB; out_t written
    //    only by the final add_ln).
    //  - ff1b/ff2b in qc/qp regions (dead after CA scores).
    bf16* tgt_b    = sc;
    bf16* mem_b    = sc;
    bf16* mempos_b = sc + 6291456;
    bf16* wb       = (bf16*)d_out;
    const size_t WSTEP = 589824;  // 768*768
    bf16* tp_b   = (bf16*)((char*)d_out + 12582912);
    bf16* qpin_b = tp_b + 3145728;
    bf16* ff1b   = qc;
    bf16* ff2b   = qp;

    float* out_t    = (float*)d_out;        // (L,B,D)
    float* out_att  = out_t + 3145728;      // (B,L,S)
    float* out_satt = out_att + 4194304;    // (B,L,L)

    const dim3 blk(256);
    const float SCALE = 0.0625f;

    // ---- cvt pass 1: 10 weights + tgt + tgt_pos(persistent) ----
    {
        CvtJobs C = {};
        for (int i = 0; i < 5; i++) C.j[i] = {sa_w[i], nullptr, wb + i * WSTEP, 73728};
        for (int i = 0; i < 3; i++) C.j[5 + i] = {ca_w[2 + i], nullptr, wb + (5 + i) * WSTEP, 73728};
        C.j[8]  = {ca_w[0], nullptr, wb + 8 * WSTEP, 73728};
        C.j[9]  = {ca_w[1], nullptr, wb + 9 * WSTEP, 73728};
        C.j[10] = {tgt,     nullptr, tgt_b, 393216};
        C.j[11] = {tgt_pos, nullptr, tp_b,  393216};
        cvt_multi<<<dim3(288, 12), blk, 0, stream>>>(C);
    }

    // ---- self attention ----
    {
        JobsB J = {};
        J.j[0] = {tp_b,  wb + 0 * WSTEP, sa_b[0], qc, 0};
        J.j[1] = {tgt_b, wb + 1 * WSTEP, sa_b[1], qp, 0};
        J.j[2] = {tp_b,  wb + 2 * WSTEP, sa_b[2], kc, 0};
        J.j[3] = {tgt_b, wb + 3 * WSTEP, sa_b[3], kp, 0};
        J.j[4] = {tgt_b, wb + 4 * WSTEP, sa_b[4], vv, 0};
        gemm_bb<<<dim3(6, 32, 5), blk, 0, stream>>>(J, 768, 768, 768, 768);
    }
    attn_scores<<<dim3(4, 4, 48), blk, 0, stream>>>(qc, qp, kc, kp, sc, 512, 512, SCALE);
    softmax_mean<2><<<dim3(512, 8), blk, 0, stream>>>(sc, out_satt, 512);
    attn_pv_sk<<<dim3(4, 2, 48), blk, 0, stream>>>(sc, vv, pv_sa, PSTRIDE, 512, 512);
    gemm_sk3<<<dim3(6, 32, 2), blk, 0, stream>>>(pv_sa, pv_sa + PSTRIDE, 768,
                                                 sa_w[5], 768, op, PSTRIDE, 768, 384);
    add_ln_p<2, float, bf16><<<dim3(4096), blk, 0, stream>>>(tgt, op, PSTRIDE, sa_b[5],
                                                             ln_g[0], ln_b[0], t1);

    // ---- cvt pass 2: memory, memory_pos, qp-input = bf16(t1 + tgt_pos2) ----
    {
        CvtJobs C = {};
        C.j[0] = {memory,     nullptr, mem_b,    786432};
        C.j[1] = {memory_pos, nullptr, mempos_b, 786432};
        C.j[2] = {tgt_pos2,   t1,      qpin_b,   393216};
        cvt_multi<<<dim3(288, 3), blk, 0, stream>>>(C);
    }

    // ---- cross attention ----
    {
        JobsB J = {};
        J.j[0] = {tp_b,   wb + 8 * WSTEP, ca_b[0], qc, 0};
        J.j[1] = {qpin_b, wb + 9 * WSTEP, ca_b[1], qp, 0};
        gemm_bb<<<dim3(6, 32, 2), blk, 0, stream>>>(J, 768, 768, 768, 768);
    }
    {
        JobsB J = {};
        J.j[0] = {mem_b,    wb + 5 * WSTEP, ca_b[2], kc, 0};
        J.j[1] = {mempos_b, wb + 6 * WSTEP, ca_b[3], kp, 0};
        J.j[2] = {mempos_b, wb + 7 * WSTEP, ca_b[4], vv, 0};
        gemm_bb<<<dim3(6, 64, 3), blk, 0, stream>>>(J, 768, 768, 768, 768);
    }
    attn_scores<<<dim3(8, 4, 48), blk, 0, stream>>>(qc, qp, kc, kp, sc, 512, 1024, SCALE);
    // ---- cvt pass 3: FFN weights into dead qc/qp ----
    {
        CvtJobs C = {};
        C.j[0] = {ff1_w, nullptr, ff1b, 196608};
        C.j[1] = {ff2_w, nullptr, ff2b, 196608};
        cvt_multi<<<dim3(288, 2), blk, 0, stream>>>(C);
    }
    softmax_mean<4><<<dim3(512, 8), blk, 0, stream>>>(sc, out_att, 512);
    attn_pv_sk<<<dim3(4, 2, 48), blk, 0, stream>>>(sc, vv, pv_ca, PSTRIDE, 512, 1024);
    gemm_sk3<<<dim3(6, 32, 2), blk, 0, stream>>>(pv_ca, pv_ca + PSTRIDE, 768,
                                                 ca_w[5], 768, op, PSTRIDE, 768, 384);
    add_ln_p<2, bf16, bf16><<<dim3(4096), blk, 0, stream>>>(t1, op, PSTRIDE, ca_b[5],
                                                            ln_g[1], ln_b[1], tca);

    // ---- FFN ----
    {
        JobsB J = {};
        J.j[0] = {tca, ff1b, ff1_b, ffh, 1};
        gemm_bb<<<dim3(16, 32, 1), blk, 0, stream>>>(J, 768, 768, 2048, 768);
    }
    gemm_sk_bb<<<dim3(6, 32, 4), blk, 0, stream>>>(ffh, 2048, ff2b, 2048,
                                                   fp, PSTRIDE, 768, 512);
    add_ln_p<4, bf16, float><<<dim3(4096), blk, 0, stream>>>(tca, fp, PSTRIDE, ff2_b,
                                                             ln_g[2], ln_b[2], out_t);
}

// Round 8
// 613.311 us; speedup vs baseline: 1.2729x; 1.0179x over previous
//
#include <hip/hip_runtime.h>

// Conditional-DETR decoder layer, MI355X gfx950.
// R14 green @ 624.3 us. Top: CA kv gemm_bb 54 us; MfmaUtil 20.8% = exactly the
// 29GF MFMA floor; HBM 15.6%. Single-buffered 2-barrier K-step exposes ~600cy
// HBM latency per step (issue->vmcnt(0)->MFMA->barrier serial).
// R15 (this):
//  1) T3-min single-barrier LDS double-buffer in gemm_bb/gemm_sk_bb/
//     attn_scores: STAGE(k+1 -> buf^1) issued BEFORE compute(buf); one
//     __syncthreads per step (vmcnt+lgkm drain = required semantics).
//  2) out-projs -> bf16 gload_lds path: cvt ff-mode fuses bf16(pv0+pv1)
//     (bit-identical to gemm_sk3's ld8ff) + w5 cvt; out-proj = gemm_sk_bb.
//     SA fuse -> kc region (dead); CA fuse -> vv region (dead after CA PV).
// absmax must stay exactly 0.03125. Predict CA kv 54->~40 (LDS 32768),
// out-projs ~45->~27 each; total 624 -> ~540-560.

typedef __bf16 bf16;
typedef __attribute__((ext_vector_type(8))) __bf16 bf16x8;
typedef __attribute__((ext_vector_type(4))) float f32x4;

#define D_MODEL 768
#define NH 6
#define HD 128
#define ROWSTRIDE (8 * D_MODEL)  // 6144 (B*D)

// XCD-aware chunked swizzle: requires gridDim.x*y*z % 8 == 0 (all our grids).
__device__ inline void swz_xyz(int& x, int& y, int& z) {
    const int nx = gridDim.x, ny = gridDim.y;
    const int n = nx * ny * gridDim.z;
    const int flat = blockIdx.x + nx * (blockIdx.y + ny * blockIdx.z);
    const int t = (flat & 7) * (n >> 3) + (flat >> 3);
    x = t % nx;
    const int r = t / nx;
    y = r % ny;
    z = r / ny;
}

// global->LDS direct DMA, 16 B per lane. Dest is wave-uniform base + lane*16.
__device__ __forceinline__ void gld16(const bf16* g, bf16* l) {
    __builtin_amdgcn_global_load_lds(
        (const __attribute__((address_space(1))) unsigned int*)g,
        (__attribute__((address_space(3))) unsigned int*)l, 16, 0, 0);
}

// 8-elem staging loaders -> bf16x8
__device__ inline bf16x8 ld8f(const float* p) {
    f32x4 a = *(const f32x4*)p, b = *(const f32x4*)(p + 4);
    bf16x8 r;
#pragma unroll
    for (int i = 0; i < 4; i++) { r[i] = (bf16)a[i]; r[i + 4] = (bf16)b[i]; }
    return r;
}
__device__ inline bf16x8 ld8bf(const bf16* p, const float* q) {  // bf16 + f32
    bf16x8 x = *(const bf16x8*)p;
    f32x4 a = *(const f32x4*)q, b = *(const f32x4*)(q + 4);
    bf16x8 r;
#pragma unroll
    for (int i = 0; i < 4; i++) { r[i] = (bf16)((float)x[i] + a[i]); r[i + 4] = (bf16)((float)x[i + 4] + b[i]); }
    return r;
}
__device__ inline bf16x8 ld8ff(const float* p, const float* q) {  // f32 + f32
    f32x4 a = *(const f32x4*)p, b = *(const f32x4*)(p + 4);
    f32x4 c = *(const f32x4*)q, d = *(const f32x4*)(q + 4);
    bf16x8 r;
#pragma unroll
    for (int i = 0; i < 4; i++) { r[i] = (bf16)(a[i] + c[i]); r[i + 4] = (bf16)(b[i] + d[i]); }
    return r;
}

// ---------------------------------------------------------------------------
// Multi-segment conversion (grid-stride; blockIdx.y = job).
// src2 != null: dst = bf16(src + src2). add != null: dst = bf16((float)add + src).
// else: dst = bf16(src).
struct CvtJob { const float* src; const float* src2; const bf16* add; bf16* dst; int nvec; };
struct CvtJobs { CvtJob j[12]; };

__global__ __launch_bounds__(256) void cvt_multi(CvtJobs jobs)
{
    const CvtJob jb = jobs.j[blockIdx.y];
    const int stride = gridDim.x * 256;
    if (jb.src2) {
        for (int i = blockIdx.x * 256 + threadIdx.x; i < jb.nvec; i += stride)
            *(bf16x8*)(jb.dst + (size_t)i * 8) = ld8ff(jb.src + (size_t)i * 8, jb.src2 + (size_t)i * 8);
    } else if (jb.add) {
        for (int i = blockIdx.x * 256 + threadIdx.x; i < jb.nvec; i += stride)
            *(bf16x8*)(jb.dst + (size_t)i * 8) = ld8bf(jb.add + (size_t)i * 8, jb.src + (size_t)i * 8);
    } else {
        for (int i = blockIdx.x * 256 + threadIdx.x; i < jb.nvec; i += stride)
            *(bf16x8*)(jb.dst + (size_t)i * 8) = ld8f(jb.src + (size_t)i * 8);
    }
}

// ---------------------------------------------------------------------------
// All-bf16 multi-job GEMM, gload_lds staging, single-barrier LDS dbuf.
struct JobB { const bf16* A; const bf16* W; const float* bias; bf16* C; int relu; };
struct JobsB { JobB j[5]; };

__global__ __launch_bounds__(256) void gemm_bb(
    JobsB jobs, int lda, int ldw, int ldc, int K)
{
    __shared__ __align__(16) bf16 As[2][128 * 32];
    __shared__ __align__(16) bf16 Bs[2][128 * 32];
    int bx, by, bz;
    swz_xyz(bx, by, bz);
    const JobB jb = jobs.j[bz];
    const int bm = by * 128, bn = bx * 128;
    const int tid = threadIdx.x;
    const int wave = tid >> 6, lane = tid & 63;
    const int wm = (wave >> 1) * 64, wn = (wave & 1) * 64;
    const int quad = lane >> 4, m16 = lane & 15;
    const int crow = lane >> 2, ccol = (lane & 3) * 8;
    const bf16* a0 = jb.A + (size_t)(bm + wave * 32 + crow) * lda + ccol;
    const bf16* a1 = a0 + (size_t)16 * lda;
    const bf16* w0 = jb.W + (size_t)(bn + wave * 32 + crow) * ldw + ccol;
    const bf16* w1 = w0 + (size_t)16 * ldw;
    const int wo = wave * 1024;
    f32x4 acc[4][4] = {};
    gld16(a0, As[0] + wo);
    gld16(a1, As[0] + wo + 512);
    gld16(w0, Bs[0] + wo);
    gld16(w1, Bs[0] + wo + 512);
    __syncthreads();
    int cur = 0;
    for (int k0 = 0; k0 < K; k0 += 32) {
        const int kn = k0 + 32;
        if (kn < K) {
            bf16* dA = As[cur ^ 1] + wo;
            bf16* dB = Bs[cur ^ 1] + wo;
            gld16(a0 + kn, dA);
            gld16(a1 + kn, dA + 512);
            gld16(w0 + kn, dB);
            gld16(w1 + kn, dB + 512);
        }
        const bf16* rA = As[cur];
        const bf16* rB = Bs[cur];
        bf16x8 af[4], bfr[4];
#pragma unroll
        for (int i = 0; i < 4; i++) {
            af[i]  = *(const bf16x8*)&rA[(wm + i * 16 + m16) * 32 + quad * 8];
            bfr[i] = *(const bf16x8*)&rB[(wn + i * 16 + m16) * 32 + quad * 8];
        }
#pragma unroll
        for (int i = 0; i < 4; i++)
#pragma unroll
            for (int j = 0; j < 4; j++)
                acc[i][j] = __builtin_amdgcn_mfma_f32_16x16x32_bf16(af[i], bfr[j], acc[i][j], 0, 0, 0);
        __syncthreads();
        cur ^= 1;
    }
#pragma unroll
    for (int j = 0; j < 4; j++) {
        const int col = bn + wn + j * 16 + m16;
        const float bv = jb.bias[col];
#pragma unroll
        for (int i = 0; i < 4; i++)
#pragma unroll
            for (int r = 0; r < 4; r++) {
                const int row = bm + wm + i * 16 + quad * 4 + r;
                float val = acc[i][j][r] + bv;
                if (jb.relu) val = fmaxf(val, 0.f);
                jb.C[(size_t)row * ldc + col] = (bf16)val;
            }
    }
}

// ---------------------------------------------------------------------------
// All-bf16 split-K GEMM, gload_lds staging, dbuf, fp32 partials.
__global__ __launch_bounds__(256) void gemm_sk_bb(
    const bf16* __restrict__ A, int lda, const bf16* __restrict__ W, int ldw,
    float* __restrict__ Cp, size_t cstride, int ldc, int Ks)
{
    __shared__ __align__(16) bf16 As[2][128 * 32];
    __shared__ __align__(16) bf16 Bs[2][128 * 32];
    int bx, by, bz;
    swz_xyz(bx, by, bz);
    const int bm = by * 128, bn = bx * 128;
    const int kbase = bz * Ks;
    const int tid = threadIdx.x;
    const int wave = tid >> 6, lane = tid & 63;
    const int wm = (wave >> 1) * 64, wn = (wave & 1) * 64;
    const int quad = lane >> 4, m16 = lane & 15;
    const int crow = lane >> 2, ccol = (lane & 3) * 8;
    const bf16* a0 = A + (size_t)(bm + wave * 32 + crow) * lda + kbase + ccol;
    const bf16* a1 = a0 + (size_t)16 * lda;
    const bf16* w0 = W + (size_t)(bn + wave * 32 + crow) * ldw + kbase + ccol;
    const bf16* w1 = w0 + (size_t)16 * ldw;
    const int wo = wave * 1024;
    f32x4 acc[4][4] = {};
    gld16(a0, As[0] + wo);
    gld16(a1, As[0] + wo + 512);
    gld16(w0, Bs[0] + wo);
    gld16(w1, Bs[0] + wo + 512);
    __syncthreads();
    int cur = 0;
    for (int k0 = 0; k0 < Ks; k0 += 32) {
        const int kn = k0 + 32;
        if (kn < Ks) {
            bf16* dA = As[cur ^ 1] + wo;
            bf16* dB = Bs[cur ^ 1] + wo;
            gld16(a0 + kn, dA);
            gld16(a1 + kn, dA + 512);
            gld16(w0 + kn, dB);
            gld16(w1 + kn, dB + 512);
        }
        const bf16* rA = As[cur];
        const bf16* rB = Bs[cur];
        bf16x8 af[4], bfr[4];
#pragma unroll
        for (int i = 0; i < 4; i++) {
            af[i]  = *(const bf16x8*)&rA[(wm + i * 16 + m16) * 32 + quad * 8];
            bfr[i] = *(const bf16x8*)&rB[(wn + i * 16 + m16) * 32 + quad * 8];
        }
#pragma unroll
        for (int i = 0; i < 4; i++)
#pragma unroll
            for (int j = 0; j < 4; j++)
                acc[i][j] = __builtin_amdgcn_mfma_f32_16x16x32_bf16(af[i], bfr[j], acc[i][j], 0, 0, 0);
        __syncthreads();
        cur ^= 1;
    }
    float* out = Cp + (size_t)bz * cstride;
#pragma unroll
    for (int j = 0; j < 4; j++) {
        const int col = bn + wn + j * 16 + m16;
#pragma unroll
        for (int i = 0; i < 4; i++)
#pragma unroll
            for (int r = 0; r < 4; r++) {
                const int row = bm + wm + i * 16 + quad * 4 + r;
                out[(size_t)row * ldc + col] = acc[i][j][r];
            }
    }
}

// ---------------------------------------------------------------------------
// scores[bh,l,s] = scale*(qc.kc + qp.kp), K=256. Dbuf gload_lds both tiles.
__global__ __launch_bounds__(256) void attn_scores(
    const bf16* __restrict__ qc, const bf16* __restrict__ qp,
    const bf16* __restrict__ kc, const bf16* __restrict__ kp,
    bf16* __restrict__ scores, int Lq, int S, float scale)
{
    __shared__ __align__(16) bf16 As[2][128 * 32];
    __shared__ __align__(16) bf16 Bs[2][128 * 32];
    int bx, by, bz;
    swz_xyz(bx, by, bz);
    const int bh = bz;
    const int b = bh / NH, h = bh % NH;
    const int bm = by * 128, bn = bx * 128;
    const int tid = threadIdx.x;
    const int wave = tid >> 6, lane = tid & 63;
    const int wm = (wave >> 1) * 64, wn = (wave & 1) * 64;
    const int quad = lane >> 4, m16 = lane & 15;
    const int crow = lane >> 2, ccol = (lane & 3) * 8;
    const size_t hb = (size_t)b * D_MODEL + h * HD;
    const size_t ar0 = (size_t)(bm + wave * 32 + crow) * ROWSTRIDE + hb + ccol;
    const size_t ar1 = ar0 + (size_t)16 * ROWSTRIDE;
    const size_t br0 = (size_t)(bn + wave * 32 + crow) * ROWSTRIDE + hb + ccol;
    const size_t br1 = br0 + (size_t)16 * ROWSTRIDE;
    const int wo = wave * 1024;
    f32x4 acc[4][4] = {};
    gld16(qc + ar0, As[0] + wo);
    gld16(qc + ar1, As[0] + wo + 512);
    gld16(kc + br0, Bs[0] + wo);
    gld16(kc + br1, Bs[0] + wo + 512);
    __syncthreads();
    int cur = 0;
    for (int k0 = 0; k0 < 256; k0 += 32) {
        const int kn = k0 + 32;
        if (kn < 256) {
            const bf16* qsrc = (kn < 128) ? qc : qp;
            const bf16* ksrc = (kn < 128) ? kc : kp;
            const int kcol = kn & 127;
            bf16* dA = As[cur ^ 1] + wo;
            bf16* dB = Bs[cur ^ 1] + wo;
            gld16(qsrc + ar0 + kcol, dA);
            gld16(qsrc + ar1 + kcol, dA + 512);
            gld16(ksrc + br0 + kcol, dB);
            gld16(ksrc + br1 + kcol, dB + 512);
        }
        const bf16* rA = As[cur];
        const bf16* rB = Bs[cur];
        bf16x8 af[4], bfr[4];
#pragma unroll
        for (int i = 0; i < 4; i++) {
            af[i]  = *(const bf16x8*)&rA[(wm + i * 16 + m16) * 32 + quad * 8];
            bfr[i] = *(const bf16x8*)&rB[(wn + i * 16 + m16) * 32 + quad * 8];
        }
#pragma unroll
        for (int i = 0; i < 4; i++)
#pragma unroll
            for (int j = 0; j < 4; j++)
                acc[i][j] = __builtin_amdgcn_mfma_f32_16x16x32_bf16(af[i], bfr[j], acc[i][j], 0, 0, 0);
        __syncthreads();
        cur ^= 1;
    }
    bf16* sb = scores + (size_t)bh * Lq * S;
#pragma unroll
    for (int i = 0; i < 4; i++)
#pragma unroll
        for (int j = 0; j < 4; j++)
#pragma unroll
            for (int r = 0; r < 4; r++)
                sb[(size_t)(bm + wm + i * 16 + quad * 4 + r) * S + bn + wn + j * 16 + m16]
                    = (bf16)(acc[i][j][r] * scale);
}

// ---------------------------------------------------------------------------
// Fused softmax + head-mean. One block per (b,l): all NH=6 head rows.
template <int N>
__global__ __launch_bounds__(256) void softmax_mean(
    bf16* __restrict__ scores, float* __restrict__ att, int Lq)
{
    const int S = N << 8;
    const int l = blockIdx.x, b = blockIdx.y;
    const int tid = threadIdx.x;
    __shared__ float red[4], red2[4];
    float macc[N];
#pragma unroll
    for (int i = 0; i < N; i++) macc[i] = 0.f;
    for (int h = 0; h < NH; h++) {
        bf16* p = scores + ((size_t)(b * NH + h) * Lq + l) * S;
        float vals[N];
        float mx = -1e30f;
#pragma unroll
        for (int i = 0; i < N; i++) { vals[i] = (float)p[tid + (i << 8)]; mx = fmaxf(mx, vals[i]); }
        for (int off = 32; off; off >>= 1) mx = fmaxf(mx, __shfl_xor(mx, off, 64));
        if ((tid & 63) == 0) red[tid >> 6] = mx;
        __syncthreads();
        mx = fmaxf(fmaxf(red[0], red[1]), fmaxf(red[2], red[3]));
        float sum = 0.f;
#pragma unroll
        for (int i = 0; i < N; i++) { vals[i] = __expf(vals[i] - mx); sum += vals[i]; }
        for (int off = 32; off; off >>= 1) sum += __shfl_xor(sum, off, 64);
        if ((tid & 63) == 0) red2[tid >> 6] = sum;
        __syncthreads();
        const float inv = 1.f / (red2[0] + red2[1] + red2[2] + red2[3]);
#pragma unroll
        for (int i = 0; i < N; i++) {
            const float w = vals[i] * inv;
            p[tid + (i << 8)] = (bf16)w;
            macc[i] += w;
        }
    }
    float* ao = att + ((size_t)b * Lq + l) * S;
#pragma unroll
    for (int i = 0; i < N; i++) ao[tid + (i << 8)] = macc[i] * (1.f / 6.f);
}

// ---------------------------------------------------------------------------
// Split-S PV. A-side (softmax weights) via gload_lds; V transposed reg-scatter.
__global__ __launch_bounds__(256) void attn_pv_sk(
    const bf16* __restrict__ wsm, const bf16* __restrict__ v,
    float* __restrict__ Pv, size_t pstride, int Lq, int S)
{
    __shared__ __align__(16) bf16 As[128 * 32];
    __shared__ __align__(16) bf16 BsT[128][40];
    int bx, by, bz;
    swz_xyz(bx, by, bz);
    const int bh = bz;
    const int b = bh / NH, h = bh % NH;
    const int bm = bx * 128;
    const int kbase = by * (S >> 1);
    const int tid = threadIdx.x;
    const int wave = tid >> 6, lane = tid & 63;
    const int wm = (wave >> 1) * 64, wn = (wave & 1) * 64;
    const int quad = lane >> 4, m16 = lane & 15;
    const int crow = lane >> 2, ccol = (lane & 3) * 8;
    const int kk0 = tid >> 4, e0 = (tid & 15) * 8;
    f32x4 acc[4][4] = {};
    const bf16* wbase = wsm + (size_t)(bh * Lq + bm) * S + kbase;
    const size_t vb = (size_t)b * D_MODEL + h * HD;
    const bf16* a0 = wbase + (size_t)(wave * 32 + crow) * S + ccol;
    const bf16* a1 = a0 + (size_t)16 * S;
    bf16* lA = As + wave * 1024;
    bf16x8 v0, v1;
    v0 = *(const bf16x8*)(v + (size_t)(kbase + kk0) * ROWSTRIDE + vb + e0);
    v1 = *(const bf16x8*)(v + (size_t)(kbase + kk0 + 16) * ROWSTRIDE + vb + e0);
    for (int k0 = 0; k0 < (S >> 1); k0 += 32) {
        gld16(a0 + k0, lA);
        gld16(a1 + k0, lA + 512);
#pragma unroll
        for (int i = 0; i < 8; i++) { BsT[e0 + i][kk0] = v0[i]; BsT[e0 + i][kk0 + 16] = v1[i]; }
        __syncthreads();
        const int kn = k0 + 32;
        if (kn < (S >> 1)) {
            v0 = *(const bf16x8*)(v + (size_t)(kbase + kn + kk0) * ROWSTRIDE + vb + e0);
            v1 = *(const bf16x8*)(v + (size_t)(kbase + kn + kk0 + 16) * ROWSTRIDE + vb + e0);
        }
        bf16x8 af[4], bfr[4];
#pragma unroll
        for (int i = 0; i < 4; i++) {
            af[i]  = *(const bf16x8*)&As[(wm + i * 16 + m16) * 32 + quad * 8];
            bfr[i] = *(const bf16x8*)&BsT[wn + i * 16 + m16][quad * 8];
        }
#pragma unroll
        for (int i = 0; i < 4; i++)
#pragma unroll
            for (int j = 0; j < 4; j++)
                acc[i][j] = __builtin_amdgcn_mfma_f32_16x16x32_bf16(af[i], bfr[j], acc[i][j], 0, 0, 0);
        __syncthreads();
    }
    float* out = Pv + by * pstride;
#pragma unroll
    for (int i = 0; i < 4; i++)
#pragma unroll
        for (int j = 0; j < 4; j++)
#pragma unroll
            for (int r = 0; r < 4; r++)
                out[(size_t)(bm + wm + i * 16 + quad * 4 + r) * ROWSTRIDE + vb + wn + j * 16 + m16]
                    = acc[i][j][r];
}

// ---------------------------------------------------------------------------
// out = LN(resid + sum_{p<NP} P[p] + xbias) * g + be.
template <int NP, typename TR, typename TO>
__global__ __launch_bounds__(256) void add_ln_p(
    const TR* __restrict__ resid, const float* __restrict__ P, size_t pstride,
    const float* __restrict__ xbias,
    const float* __restrict__ g, const float* __restrict__ be, TO* __restrict__ out)
{
    const size_t base = (size_t)blockIdx.x * D_MODEL;
    const int tid = threadIdx.x;
    float v[3];
#pragma unroll
    for (int i = 0; i < 3; i++) {
        const int c = tid + (i << 8);
        float x = xbias[c];
#pragma unroll
        for (int p = 0; p < NP; p++) x += P[p * pstride + base + c];
        v[i] = (float)resid[base + c] + x;
    }
    float s = v[0] + v[1] + v[2];
    float s2 = v[0] * v[0] + v[1] * v[1] + v[2] * v[2];
    for (int off = 32; off; off >>= 1) { s += __shfl_xor(s, off, 64); s2 += __shfl_xor(s2, off, 64); }
    __shared__ float rs[4], rs2[4];
    if ((tid & 63) == 0) { rs[tid >> 6] = s; rs2[tid >> 6] = s2; }
    __syncthreads();
    s = rs[0] + rs[1] + rs[2] + rs[3];
    s2 = rs2[0] + rs2[1] + rs2[2] + rs2[3];
    const float mean = s * (1.f / 768.f);
    const float var = s2 * (1.f / 768.f) - mean * mean;
    const float inv = rsqrtf(var + 1e-5f);
#pragma unroll
    for (int i = 0; i < 3; i++) {
        const int c = tid + (i << 8);
        out[base + c] = (TO)((v[i] - mean) * inv * g[c] + be[c]);
    }
}

// ---------------------------------------------------------------------------
extern "C" void kernel_launch(void* const* d_in, const int* in_sizes, int n_in,
                              void* d_out, int out_size, void* d_ws, size_t ws_size,
                              hipStream_t stream)
{
    const float* tgt        = (const float*)d_in[0];
    const float* memory     = (const float*)d_in[1];
    const float* tgt_pos    = (const float*)d_in[2];
    const float* memory_pos = (const float*)d_in[3];
    const float* tgt_pos2   = (const float*)d_in[4];
    const float *sa_w[6], *sa_b[6], *ca_w[6], *ca_b[6];
    for (int i = 0; i < 6; i++) {
        sa_w[i] = (const float*)d_in[5 + 2 * i];  sa_b[i] = (const float*)d_in[6 + 2 * i];
        ca_w[i] = (const float*)d_in[17 + 2 * i]; ca_b[i] = (const float*)d_in[18 + 2 * i];
    }
    const float* ff1_w = (const float*)d_in[29]; const float* ff1_b = (const float*)d_in[30];
    const float* ff2_w = (const float*)d_in[31]; const float* ff2_b = (const float*)d_in[32];
    const float* ln_g[3] = {(const float*)d_in[33], (const float*)d_in[35], (const float*)d_in[37]};
    const float* ln_b[3] = {(const float*)d_in[34], (const float*)d_in[36], (const float*)d_in[38]};

    // ---- workspace (106,954,752 B) ----
    char* ws = (char*)d_ws;
    bf16* qc  = (bf16*)(ws);                // [0, 6291456)
    bf16* qp  = (bf16*)(ws + 6291456);      // [6291456, 12582912)
    bf16* kc  = (bf16*)(ws + 12582912);     // [12582912, 25165824)
    bf16* kp  = (bf16*)(ws + 25165824);     // [25165824, 37748736)
    bf16* vv  = (bf16*)(ws + 37748736);     // [37748736, 50331648)
    bf16* t1  = (bf16*)(ws + 50331648);     // [50331648, 56623104)
    bf16* sc  = (bf16*)(ws + 56623104);     // [56623104, 106954752) 50.33 MB
    const size_t PSTRIDE = 3145728;  // floats per 12.58 MB slice
    float* pv_sa = (float*)(ws + 81788928);  // sc_hi: SA PV pair (sc_lo = SA scores live)
    float* pv_ca = (float*)(ws + 12582912);  // kc+kp: dead after CA scores
    float* op    = (float*)(ws + 56623104);  // sc_lo: out-proj pair (both phases)
    float* fp    = (float*)(ws + 56623104);  // FFN2 4-slice = full sc (dead)
    bf16*  tca   = kc;                       // Pv_ca dead after CA out-proj
    bf16*  ffh   = kp;                       // 16.78 MB over dead kp+vv

    // bf16 staging (liveness-checked):
    //  - tgt_b in sc[0..6.3 MB): live only during SA proj.
    //  - tp_b/qpin_b in d_out out_att region: free until CA softmax_mean.
    //  - 10 weight mats bf16 in out_t region (final add_ln writes out_t last).
    //  - ff1b/ff2b in qc/qp (dead after CA scores).
    //  - savA (bf16(pv_sa0+pv_sa1)) + saw5b in kc region (dead until CA kv).
    //  - cavA (bf16(pv_ca0+pv_ca1)) + caw5b in vv region (dead after CA PV;
    //    ffh written later overlaps only after CA out-proj consumed them).
    bf16* tgt_b    = sc;
    bf16* mem_b    = sc;
    bf16* mempos_b = sc + 6291456;
    bf16* wb       = (bf16*)d_out;
    const size_t WSTEP = 589824;  // 768*768
    bf16* tp_b   = (bf16*)((char*)d_out + 12582912);
    bf16* qpin_b = tp_b + 3145728;
    bf16* ff1b   = qc;
    bf16* ff2b   = qp;
    bf16* savA   = kc;                      // 6.29 MB
    bf16* saw5b  = kc + 3145728;            // +1.18 MB
    bf16* cavA   = vv;                      // 6.29 MB
    bf16* caw5b  = vv + 3145728;            // +1.18 MB

    float* out_t    = (float*)d_out;        // (L,B,D)
    float* out_att  = out_t + 3145728;      // (B,L,S)
    float* out_satt = out_att + 4194304;    // (B,L,L)

    const dim3 blk(256);
    const float SCALE = 0.0625f;

    // ---- cvt pass 1: 10 weights + tgt + tgt_pos(persistent) ----
    {
        CvtJobs C = {};
        for (int i = 0; i < 5; i++) C.j[i] = {sa_w[i], nullptr, nullptr, wb + i * WSTEP, 73728};
        for (int i = 0; i < 3; i++) C.j[5 + i] = {ca_w[2 + i], nullptr, nullptr, wb + (5 + i) * WSTEP, 73728};
        C.j[8]  = {ca_w[0], nullptr, nullptr, wb + 8 * WSTEP, 73728};
        C.j[9]  = {ca_w[1], nullptr, nullptr, wb + 9 * WSTEP, 73728};
        C.j[10] = {tgt,     nullptr, nullptr, tgt_b, 393216};
        C.j[11] = {tgt_pos, nullptr, nullptr, tp_b,  393216};
        cvt_multi<<<dim3(288, 12), blk, 0, stream>>>(C);
    }

    // ---- self attention ----
    {
        JobsB J = {};
        J.j[0] = {tp_b,  wb + 0 * WSTEP, sa_b[0], qc, 0};
        J.j[1] = {tgt_b, wb + 1 * WSTEP, sa_b[1], qp, 0};
        J.j[2] = {tp_b,  wb + 2 * WSTEP, sa_b[2], kc, 0};
        J.j[3] = {tgt_b, wb + 3 * WSTEP, sa_b[3], kp, 0};
        J.j[4] = {tgt_b, wb + 4 * WSTEP, sa_b[4], vv, 0};
        gemm_bb<<<dim3(6, 32, 5), blk, 0, stream>>>(J, 768, 768, 768, 768);
    }
    attn_scores<<<dim3(4, 4, 48), blk, 0, stream>>>(qc, qp, kc, kp, sc, 512, 512, SCALE);
    softmax_mean<2><<<dim3(512, 8), blk, 0, stream>>>(sc, out_satt, 512);
    attn_pv_sk<<<dim3(4, 2, 48), blk, 0, stream>>>(sc, vv, pv_sa, PSTRIDE, 512, 512);
    // fuse: savA = bf16(pv0 + pv1); saw5b = bf16(sa_w[5])
    {
        CvtJobs C = {};
        C.j[0] = {pv_sa, pv_sa + PSTRIDE, nullptr, savA,  393216};
        C.j[1] = {sa_w[5], nullptr,       nullptr, saw5b, 73728};
        cvt_multi<<<dim3(288, 2), blk, 0, stream>>>(C);
    }
    gemm_sk_bb<<<dim3(6, 32, 2), blk, 0, stream>>>(savA, 768, saw5b, 768,
                                                   op, PSTRIDE, 768, 384);
    add_ln_p<2, float, bf16><<<dim3(4096), blk, 0, stream>>>(tgt, op, PSTRIDE, sa_b[5],
                                                             ln_g[0], ln_b[0], t1);

    // ---- cvt pass 2: memory, memory_pos, qp-input = bf16(t1 + tgt_pos2) ----
    {
        CvtJobs C = {};
        C.j[0] = {memory,     nullptr, nullptr, mem_b,    786432};
        C.j[1] = {memory_pos, nullptr, nullptr, mempos_b, 786432};
        C.j[2] = {tgt_pos2,   nullptr, t1,      qpin_b,   393216};
        cvt_multi<<<dim3(288, 3), blk, 0, stream>>>(C);
    }

    // ---- cross attention ----
    {
        JobsB J = {};
        J.j[0] = {tp_b,   wb + 8 * WSTEP, ca_b[0], qc, 0};
        J.j[1] = {qpin_b, wb + 9 * WSTEP, ca_b[1], qp, 0};
        gemm_bb<<<dim3(6, 32, 2), blk, 0, stream>>>(J, 768, 768, 768, 768);
    }
    {
        JobsB J = {};
        J.j[0] = {mem_b,    wb + 5 * WSTEP, ca_b[2], kc, 0};
        J.j[1] = {mempos_b, wb + 6 * WSTEP, ca_b[3], kp, 0};
        J.j[2] = {mempos_b, wb + 7 * WSTEP, ca_b[4], vv, 0};
        gemm_bb<<<dim3(6, 64, 3), blk, 0, stream>>>(J, 768, 768, 768, 768);
    }
    attn_scores<<<dim3(8, 4, 48), blk, 0, stream>>>(qc, qp, kc, kp, sc, 512, 1024, SCALE);
    // ---- cvt pass 3: FFN weights into dead qc/qp ----
    {
        CvtJobs C = {};
        C.j[0] = {ff1_w, nullptr, nullptr, ff1b, 196608};
        C.j[1] = {ff2_w, nullptr, nullptr, ff2b, 196608};
        cvt_multi<<<dim3(288, 2), blk, 0, stream>>>(C);
    }
    softmax_mean<4><<<dim3(512, 8), blk, 0, stream>>>(sc, out_att, 512);
    attn_pv_sk<<<dim3(4, 2, 48), blk, 0, stream>>>(sc, vv, pv_ca, PSTRIDE, 512, 1024);
    // fuse: cavA = bf16(pv0 + pv1); caw5b = bf16(ca_w[5])
    {
        CvtJobs C = {};
        C.j[0] = {pv_ca, pv_ca + PSTRIDE, nullptr, cavA,  393216};
        C.j[1] = {ca_w[5], nullptr,       nullptr, caw5b, 73728};
        cvt_multi<<<dim3(288, 2), blk, 0, stream>>>(C);
    }
    gemm_sk_bb<<<dim3(6, 32, 2), blk, 0, stream>>>(cavA, 768, caw5b, 768,
                                                   op, PSTRIDE, 768, 384);
    add_ln_p<2, bf16, bf16><<<dim3(4096), blk, 0, stream>>>(t1, op, PSTRIDE, ca_b[5],
                                                            ln_g[1], ln_b[1], tca);

    // ---- FFN ----
    {
        JobsB J = {};
        J.j[0] = {tca, ff1b, ff1_b, ffh, 1};
        gemm_bb<<<dim3(16, 32, 1), blk, 0, stream>>>(J, 768, 768, 2048, 768);
    }
    gemm_sk_bb<<<dim3(6, 32, 4), blk, 0, stream>>>(ffh, 2048, ff2b, 2048,
                                                   fp, PSTRIDE, 768, 512);
    add_ln_p<4, bf16, float><<<dim3(4096), blk, 0, stream>>>(tca, fp, PSTRIDE, ff2_b,
                                                             ln_g[2], ln_b[2], out_t);
}